// Round 18
// baseline (84.380 us; speedup 1.0000x reference)
//
#include <hip/hip_runtime.h>
#include <hip/hip_bf16.h>
#include <math.h>

#define TT 512
#define CC 1024
#define NH 16
#define NKV 8
#define HD 64
static constexpr float EPS_ = 1e-6f;

typedef short bf16x8 __attribute__((ext_vector_type(8)));
typedef float f32x4 __attribute__((ext_vector_type(4)));
typedef _Float16 half2v __attribute__((ext_vector_type(2)));

__device__ __forceinline__ ushort f2bf(float f) {
  union { __hip_bfloat16 h; ushort u; } cv;
  cv.h = __float2bfloat16(f);
  return cv.u;
}
__device__ __forceinline__ ushort f2h(float f) {
  union { _Float16 h; ushort u; } cv;
  cv.h = (_Float16)f;
  return cv.u;
}
__device__ __forceinline__ half2v bch2(uint u) {
  union { uint u; half2v h; } cv;
  cv.u = u;
  return cv.h;
}

// ---------------------------------------------------------------------------
// prep: x -> bf16 (same layout); Wq/Wk/Wv/Wo -> transposed bf16 Wt[n][k]
// ---------------------------------------------------------------------------
__global__ __launch_bounds__(256) void prep_kernel(
    const float* __restrict__ x,
    const float* __restrict__ Wq, const float* __restrict__ Wk,
    const float* __restrict__ Wv, const float* __restrict__ Wo,
    ushort* __restrict__ xb, ushort* __restrict__ Wtq, ushort* __restrict__ Wtk,
    ushort* __restrict__ Wtv, ushort* __restrict__ Wto)
{
  int b = blockIdx.x;
  if (b < 256) {
    int base = b * 2048 + threadIdx.x * 8;
    float4 f0 = *reinterpret_cast<const float4*>(&x[base]);
    float4 f1 = *reinterpret_cast<const float4*>(&x[base + 4]);
    union { ushort u[8]; uint4 v; } pk;
    pk.u[0] = f2bf(f0.x); pk.u[1] = f2bf(f0.y); pk.u[2] = f2bf(f0.z); pk.u[3] = f2bf(f0.w);
    pk.u[4] = f2bf(f1.x); pk.u[5] = f2bf(f1.y); pk.u[6] = f2bf(f1.z); pk.u[7] = f2bf(f1.w);
    *reinterpret_cast<uint4*>(&xb[base]) = pk.v;
    return;
  }
  b -= 256;
  const float* W; ushort* Wt; int ldW, tr, tc;
  if (b < 256)      { W = Wq; Wt = Wtq; ldW = 1024; tr = b >> 4;       tc = b & 15; }
  else if (b < 384) { int q = b - 256; W = Wk; Wt = Wtk; ldW = 512; tr = q >> 3; tc = q & 7; }
  else if (b < 512) { int q = b - 384; W = Wv; Wt = Wtv; ldW = 512; tr = q >> 3; tc = q & 7; }
  else              { int q = b - 512; W = Wo; Wt = Wto; ldW = 1024; tr = q >> 4; tc = q & 15; }
  const int k0 = tr * 64, n0 = tc * 64;
  __shared__ float ft[64][65];
  const int t = threadIdx.x;
#pragma unroll
  for (int it = 0; it < 4; ++it) {
    int q = t + it * 256;
    int r = q >> 4, c4 = q & 15;
    float4 f = *reinterpret_cast<const float4*>(&W[(k0 + r) * ldW + n0 + c4 * 4]);
    ft[r][c4 * 4 + 0] = f.x; ft[r][c4 * 4 + 1] = f.y;
    ft[r][c4 * 4 + 2] = f.z; ft[r][c4 * 4 + 3] = f.w;
  }
  __syncthreads();
#pragma unroll
  for (int it = 0; it < 2; ++it) {
    int q = t + it * 256;
    int n = q >> 3, kc = q & 7;
    union { ushort u[8]; uint4 v; } pk;
#pragma unroll
    for (int j = 0; j < 8; ++j) pk.u[j] = f2bf(ft[kc * 8 + j][n]);
    *reinterpret_cast<uint4*>(&Wt[(n0 + n) * 1024 + k0 + kc * 8]) = pk.v;
  }
}

// ---------------------------------------------------------------------------
// bf16 MFMA GEMM: C[64x64] = A[M][kbeg:kend] @ Bt[N][kbeg:kend]^T, fp32 out.
// ---------------------------------------------------------------------------
__device__ __forceinline__ void mfma_gemm64(
    const ushort* __restrict__ A, const ushort* __restrict__ Bt,
    float* __restrict__ C, int ldC, int row0, int col0, int kbeg, int kend)
{
  __shared__ ushort At[64][72];
  __shared__ ushort Bs[64][72];
  const int tid = threadIdx.x;
  const int lane = tid & 63, w = tid >> 6;
  const int m0 = (w & 1) * 32, n0 = (w >> 1) * 32;
  const int lr = lane & 15, lk = (lane >> 4) * 8;
  f32x4 acc[2][2] = {};
  const int sr = tid >> 2;
  const int sc = (tid & 3) * 16;
  const ushort* Ap = &A[(row0 + sr) * 1024 + sc];
  const ushort* Bp = &Bt[(col0 + sr) * 1024 + sc];

  for (int k0 = kbeg; k0 < kend; k0 += 64) {
    __syncthreads();
    uint4 a0 = *reinterpret_cast<const uint4*>(Ap + k0);
    uint4 a1 = *reinterpret_cast<const uint4*>(Ap + k0 + 8);
    uint4 b0 = *reinterpret_cast<const uint4*>(Bp + k0);
    uint4 b1 = *reinterpret_cast<const uint4*>(Bp + k0 + 8);
    *reinterpret_cast<uint4*>(&At[sr][sc]) = a0;
    *reinterpret_cast<uint4*>(&At[sr][sc + 8]) = a1;
    *reinterpret_cast<uint4*>(&Bs[sr][sc]) = b0;
    *reinterpret_cast<uint4*>(&Bs[sr][sc + 8]) = b1;
    __syncthreads();
#pragma unroll
    for (int kk = 0; kk < 2; ++kk) {
      bf16x8 af[2], bg[2];
      af[0] = *reinterpret_cast<const bf16x8*>(&At[m0 + lr][kk * 32 + lk]);
      af[1] = *reinterpret_cast<const bf16x8*>(&At[m0 + 16 + lr][kk * 32 + lk]);
      bg[0] = *reinterpret_cast<const bf16x8*>(&Bs[n0 + lr][kk * 32 + lk]);
      bg[1] = *reinterpret_cast<const bf16x8*>(&Bs[n0 + 16 + lr][kk * 32 + lk]);
#pragma unroll
      for (int mi = 0; mi < 2; ++mi)
#pragma unroll
        for (int ni = 0; ni < 2; ++ni)
          acc[mi][ni] = __builtin_amdgcn_mfma_f32_16x16x32_bf16(af[mi], bg[ni], acc[mi][ni], 0, 0, 0);
    }
  }
  const int crow = (lane >> 4) * 4, ccol = lane & 15;
#pragma unroll
  for (int mi = 0; mi < 2; ++mi)
#pragma unroll
    for (int ni = 0; ni < 2; ++ni) {
      int rb = row0 + m0 + mi * 16 + crow;
      int cc = col0 + n0 + ni * 16 + ccol;
#pragma unroll
      for (int r = 0; r < 4; ++r)
        C[(rb + r) * ldC + cc] = acc[mi][ni][r];
    }
}

// K-split-2: z = blockIdx.z selects K half; partials summed by rope_fused.
__global__ __launch_bounds__(256) void qkv_mfma_kernel(
    const ushort* __restrict__ xb,
    const ushort* __restrict__ Wtq, const ushort* __restrict__ Wtk, const ushort* __restrict__ Wtv,
    float* __restrict__ qb, float* __restrict__ kb, float* __restrict__ vb)
{
  int bx = blockIdx.x, by = blockIdx.y, z = blockIdx.z;
  const int kb0 = z * 512, kb1 = kb0 + 512;
  float* qp = qb + z * (TT * CC);
  float* kp = kb + z * (TT * 512);
  float* vp = vb + z * (TT * 512);
  if (bx < 16)      mfma_gemm64(xb, Wtq, qp, 1024, by * 64, bx * 64, kb0, kb1);
  else if (bx < 24) mfma_gemm64(xb, Wtk, kp, 512, by * 64, (bx - 16) * 64, kb0, kb1);
  else              mfma_gemm64(xb, Wtv, vp, 512, by * 64, (bx - 24) * 64, kb0, kb1);
}

// ---------------------------------------------------------------------------
// out GEMM, 32x64 tiles: grid (16,16) = 256 blocks (1/CU).
// ---------------------------------------------------------------------------
__global__ __launch_bounds__(256) void out_mfma32_kernel(
    const ushort* __restrict__ yb, const ushort* __restrict__ Wto, float* __restrict__ out)
{
  __shared__ ushort At[32][72];
  __shared__ ushort Bs[64][72];
  const int tid = threadIdx.x;
  const int lane = tid & 63, w = tid >> 6;
  const int row0 = blockIdx.y * 32, col0 = blockIdx.x * 64;
  const int m0 = (w & 1) * 16, n0 = (w >> 1) * 32;
  const int lr = lane & 15, lk = (lane >> 4) * 8;
  f32x4 acc[2] = {};
  const int srA = tid >> 3, scA = (tid & 7) * 8;
  const int srB = tid >> 2, scB = (tid & 3) * 16;
  const ushort* Ap = &yb[(row0 + srA) * 1024 + scA];
  const ushort* Bp = &Wto[(col0 + srB) * 1024 + scB];

  for (int k0 = 0; k0 < 1024; k0 += 64) {
    __syncthreads();
    uint4 a0 = *reinterpret_cast<const uint4*>(Ap + k0);
    uint4 b0 = *reinterpret_cast<const uint4*>(Bp + k0);
    uint4 b1 = *reinterpret_cast<const uint4*>(Bp + k0 + 8);
    *reinterpret_cast<uint4*>(&At[srA][scA]) = a0;
    *reinterpret_cast<uint4*>(&Bs[srB][scB]) = b0;
    *reinterpret_cast<uint4*>(&Bs[srB][scB + 8]) = b1;
    __syncthreads();
#pragma unroll
    for (int kk = 0; kk < 2; ++kk) {
      bf16x8 af = *reinterpret_cast<const bf16x8*>(&At[m0 + lr][kk * 32 + lk]);
#pragma unroll
      for (int ni = 0; ni < 2; ++ni) {
        bf16x8 bg = *reinterpret_cast<const bf16x8*>(&Bs[n0 + ni * 16 + lr][kk * 32 + lk]);
        acc[ni] = __builtin_amdgcn_mfma_f32_16x16x32_bf16(af, bg, acc[ni], 0, 0, 0);
      }
    }
  }
  const int crow = (lane >> 4) * 4, ccol = lane & 15;
#pragma unroll
  for (int ni = 0; ni < 2; ++ni)
#pragma unroll
    for (int r = 0; r < 4; ++r)
      out[(row0 + m0 + crow + r) * 1024 + col0 + n0 + ni * 16 + ccol] = acc[ni][r];
}

// ---------------------------------------------------------------------------
// Fused RoPE/RMS + transposes + fp16 packing + K-split combine.
// ---------------------------------------------------------------------------
__global__ __launch_bounds__(256) void rope_fused_kernel(
    const float* __restrict__ qb, const float* __restrict__ kb,
    const float* __restrict__ vb,
    const float* __restrict__ cosb, const float* __restrict__ sinb,
    uint* __restrict__ qh, uint* __restrict__ kth, ushort* __restrict__ vt)
{
  const int b = blockIdx.x;
  const int tid = threadIdx.x;
  const int w = tid >> 6, lane = tid & 63;

  if (b < 2048) {
    int rid = b * 4 + w;
    int t = rid >> 4, hh = rid & 15;
    const float* p0 = qb + t * 1024 + hh * 64;
    const float* p1 = p0 + TT * CC;
    float v = p0[lane] + p1[lane];
    float part = __shfl_xor(v, 32);
    int f = lane & 31;
    float c = cosb[t * 32 + f], s = sinb[t * 32 + f];
    float o = (lane < 32) ? (v * c - part * s) : (part * s + v * c);
    float ss = o * o;
#pragma unroll
    for (int off = 32; off; off >>= 1) ss += __shfl_xor(ss, off);
    float r = rsqrtf(ss * (1.0f / 64.0f) + EPS_);
    uint hv = (uint)f2h(o * r);
    uint nb = __shfl_down(hv, 1);
    if ((lane & 1) == 0)
      qh[(t * 16 + hh) * 32 + (lane >> 1)] = hv | (nb << 16);
    return;
  }

  __shared__ float ft[64][65];
  const int r16 = tid >> 4, c4 = tid & 15;

  if (b < 2112) {
    const int idx = b - 2048;
    const int g = idx >> 3, t0 = (idx & 7) * 64;
#pragma unroll 4
    for (int r = 0; r < 16; ++r) {
      int row = w * 16 + r;
      int t = t0 + row;
      float v = kb[t * 512 + g * 64 + lane] + kb[TT * 512 + t * 512 + g * 64 + lane];
      float part = __shfl_xor(v, 32);
      int f = lane & 31;
      float c = cosb[t * 32 + f], s = sinb[t * 32 + f];
      float o = (lane < 32) ? (v * c - part * s) : (part * s + v * c);
      float ss = o * o;
#pragma unroll
      for (int off = 32; off; off >>= 1) ss += __shfl_xor(ss, off);
      ft[row][lane] = o * rsqrtf(ss * (1.0f / 64.0f) + EPS_);
    }
    __syncthreads();
#pragma unroll
    for (int it = 0; it < 8; ++it) {
      int idx2 = tid + it * 256;
      int d2 = idx2 >> 6, tt = idx2 & 63;
      uint lo = (uint)f2h(ft[tt][2 * d2]);
      uint hi = (uint)f2h(ft[tt][2 * d2 + 1]);
      kth[g * 16384 + d2 * 512 + t0 + tt] = lo | (hi << 16);
    }
    return;
  }

  const int idx = b - 2112;
  const int g = idx >> 3, t0 = (idx & 7) * 64;
#pragma unroll
  for (int it = 0; it < 4; ++it) {
    int row = r16 + it * 16;
    float4 fA = *reinterpret_cast<const float4*>(&vb[(t0 + row) * 512 + g * 64 + c4 * 4]);
    float4 fB = *reinterpret_cast<const float4*>(&vb[TT * 512 + (t0 + row) * 512 + g * 64 + c4 * 4]);
    ft[row][c4 * 4 + 0] = fA.x + fB.x; ft[row][c4 * 4 + 1] = fA.y + fB.y;
    ft[row][c4 * 4 + 2] = fA.z + fB.z; ft[row][c4 * 4 + 3] = fA.w + fB.w;
  }
  __syncthreads();
#pragma unroll
  for (int it = 0; it < 4; ++it) {
    int d = r16 + it * 16;
    uint2 o;
    o.x = (uint)f2bf(ft[c4 * 4 + 0][d]) | ((uint)f2bf(ft[c4 * 4 + 1][d]) << 16);
    o.y = (uint)f2bf(ft[c4 * 4 + 2][d]) | ((uint)f2bf(ft[c4 * 4 + 3][d]) << 16);
    *reinterpret_cast<uint2*>(&vt[g * 32768 + d * 512 + t0 + c4 * 4]) = o;
  }
}

// ---------------------------------------------------------------------------
// Phase A v3: tropical scores via packed fp16.
// ---------------------------------------------------------------------------
__global__ __launch_bounds__(256) void score_kernel(
    const uint* __restrict__ qh, const uint* __restrict__ kth,
    ushort* __restrict__ Pb)
{
  const int tid = threadIdx.x;
  const int w = tid >> 6, lane = tid & 63;
  const int u = blockIdx.x * 4 + w;
  const int h = u / 576;
  const int r = u - h * 576;
  const int A = (r >= 16) + (r >= 48) + (r >= 96) + (r >= 160) +
                (r >= 240) + (r >= 336) + (r >= 448);
  const int rb = r - 8 * A * (A + 1);
  const int c4 = 16 * A + rb / (A + 1);
  const int jt = rb % (A + 1);
  const int g = h >> 1;
  const int i0 = c4 * 4;
  const int j0 = jt * 64;
  const bool diag = (jt == A);

  half2v kreg[32];
  const uint* ktp = &kth[g * 16384 + j0 + lane];
#pragma unroll
  for (int d2 = 0; d2 < 32; ++d2) kreg[d2] = bch2(ktp[d2 * 512]);

  ushort* pp = &Pb[h * (TT * TT) + i0 * 512 + j0 + lane];
  const half2v NEGBIG = {(_Float16)-60000.0f, (_Float16)-60000.0f};

#pragma unroll 2
  for (int q = 0; q < 4; ++q) {
    const uint4* qp4 = reinterpret_cast<const uint4*>(&qh[((i0 + q) * 16 + h) * 32]);
    half2v m0 = NEGBIG, m1 = NEGBIG;
#pragma unroll
    for (int it = 0; it < 8; ++it) {
      uint4 qq = qp4[it];
      half2v a0 = bch2(qq.x) + kreg[it * 4 + 0];
      half2v a1 = bch2(qq.y) + kreg[it * 4 + 1];
      half2v a2 = bch2(qq.z) + kreg[it * 4 + 2];
      half2v a3 = bch2(qq.w) + kreg[it * 4 + 3];
      m0 = __builtin_elementwise_max(m0, __builtin_elementwise_max(a0, a1));
      m1 = __builtin_elementwise_max(m1, __builtin_elementwise_max(a2, a3));
    }
    half2v mm = __builtin_elementwise_max(m0, m1);
    float s = fmaxf((float)mm[0], (float)mm[1]);
    if (diag && (j0 + lane > i0 + q)) s = -INFINITY;
    pp[q * 512] = f2bf(__expf(s));
  }
}

// ---------------------------------------------------------------------------
// Phase B: y = (P @ V) / rowsum(P) via bf16 MFMA.
// ---------------------------------------------------------------------------
__global__ __launch_bounds__(256) void pv_kernel(
    const ushort* __restrict__ Pb, const ushort* __restrict__ vt,
    ushort* __restrict__ yb)
{
  __shared__ __align__(16) ushort Ps[64][72];
  __shared__ __align__(16) ushort Vs[64][72];
  const int tid = threadIdx.x;
  const int w = tid >> 6, lane = tid & 63;
  const int bx = blockIdx.x;
  const int h = bx & 15;
  const int cc = 7 - (bx >> 4);
  const int g = h >> 1;
  const int i0 = cc * 64;
  const int rbw = w * 16;
  const int lr = lane & 15, lk = (lane >> 4) * 8;
  f32x4 acc[4] = {};
  f32x4 accl = {};

  bf16x8 ones;
#pragma unroll
  for (int e = 0; e < 8; ++e) ones[e] = (short)0x3F80;

  const int srow = tid >> 2, scol = (tid & 3) * 16;
  for (int jt = 0; jt <= cc; ++jt) {
    const int j0 = jt * 64;
    __syncthreads();
    {
      const ushort* ps = &Pb[h * (TT * TT) + (i0 + srow) * 512 + j0 + scol];
      uint4 a0 = *reinterpret_cast<const uint4*>(ps);
      uint4 a1 = *reinterpret_cast<const uint4*>(ps + 8);
      const ushort* vs = &vt[g * 32768 + srow * 512 + j0 + scol];
      uint4 b0 = *reinterpret_cast<const uint4*>(vs);
      uint4 b1 = *reinterpret_cast<const uint4*>(vs + 8);
      *reinterpret_cast<uint4*>(&Ps[srow][scol]) = a0;
      *reinterpret_cast<uint4*>(&Ps[srow][scol + 8]) = a1;
      *reinterpret_cast<uint4*>(&Vs[srow][scol]) = b0;
      *reinterpret_cast<uint4*>(&Vs[srow][scol + 8]) = b1;
    }
    __syncthreads();
#pragma unroll
    for (int kk = 0; kk < 2; ++kk) {
      bf16x8 af = *reinterpret_cast<const bf16x8*>(&Ps[rbw + lr][kk * 32 + lk]);
      accl = __builtin_amdgcn_mfma_f32_16x16x32_bf16(af, ones, accl, 0, 0, 0);
#pragma unroll
      for (int ni = 0; ni < 4; ++ni) {
        bf16x8 bg = *reinterpret_cast<const bf16x8*>(&Vs[ni * 16 + lr][kk * 32 + lk]);
        acc[ni] = __builtin_amdgcn_mfma_f32_16x16x32_bf16(af, bg, acc[ni], 0, 0, 0);
      }
    }
  }

  const int crow = (lane >> 4) * 4, ccol = lane & 15;
#pragma unroll
  for (int r = 0; r < 4; ++r) {
    int i = i0 + rbw + crow + r;
    float linv = 1.0f / accl[r];
#pragma unroll
    for (int ni = 0; ni < 4; ++ni)
      yb[i * 1024 + h * 64 + ni * 16 + ccol] = f2bf(acc[ni][r] * linv);
  }
}

// ---------------------------------------------------------------------------
// MEASUREMENT ROUND #3: prep, rope_fused, score, pv launched TWICE each (all
// pure). Delta vs R17 (56.6 us) = warm cost of those four + 4 launch gaps.
// Everything else byte-identical to R17.
// ---------------------------------------------------------------------------
extern "C" void kernel_launch(void* const* d_in, const int* in_sizes, int n_in,
                              void* d_out, int out_size, void* d_ws, size_t ws_size,
                              hipStream_t stream) {
  const float* x    = (const float*)d_in[0];
  const float* cosb = (const float*)d_in[1];
  const float* sinb = (const float*)d_in[2];
  const float* Wq   = (const float*)d_in[3];
  const float* Wk   = (const float*)d_in[4];
  const float* Wv   = (const float*)d_in[5];
  const float* Wo   = (const float*)d_in[6];
  float* out = (float*)d_out;

  float* wsf = (float*)d_ws;
  float* qbuf  = wsf;                      // 2 x 512x1024 f32 (K-split partials)
  float* kbuf  = qbuf + 2 * TT * CC;       // 2 x 512x512  f32
  float* vbuf  = kbuf + 2 * TT * 512;      // 2 x 512x512  f32
  uint*  kth   = (uint*)(vbuf + 2 * TT * 512); // 8x32x512 uint (half2 K^T)
  uint*  qh    = kth + 8 * 32 * 512;       // 512x16x32 uint (half2 q)
  ushort* wsu = (ushort*)(qh + TT * 16 * 32);
  ushort* xb  = wsu;                       // 512x1024 bf16
  ushort* yb  = xb + TT * CC;              // 512x1024 bf16
  ushort* Pb  = yb + TT * CC;              // 16x512x512 bf16 (P matrix)
  ushort* vtb = Pb + NH * TT * TT;         // 8x64x512 bf16 (V^T)
  ushort* Wtq = vtb + 8 * 64 * 512;        // 1024x1024 bf16
  ushort* Wtk = Wtq + CC * CC;             // 512x1024 bf16
  ushort* Wtv = Wtk + 512 * CC;            // 512x1024 bf16
  ushort* Wto = Wtv + 512 * CC;            // 1024x1024 bf16

  prep_kernel<<<dim3(1024), 256, 0, stream>>>(x, Wq, Wk, Wv, Wo, xb, Wtq, Wtk, Wtv, Wto);
  prep_kernel<<<dim3(1024), 256, 0, stream>>>(x, Wq, Wk, Wv, Wo, xb, Wtq, Wtk, Wtv, Wto); // probe
  qkv_mfma_kernel<<<dim3(32, 8, 2), 256, 0, stream>>>(xb, Wtq, Wtk, Wtv, qbuf, kbuf, vbuf);
  rope_fused_kernel<<<dim3(2176), 256, 0, stream>>>(qbuf, kbuf, vbuf, cosb, sinb, qh, kth, vtb);
  rope_fused_kernel<<<dim3(2176), 256, 0, stream>>>(qbuf, kbuf, vbuf, cosb, sinb, qh, kth, vtb); // probe
  score_kernel<<<dim3(2304), 256, 0, stream>>>(qh, kth, Pb);
  score_kernel<<<dim3(2304), 256, 0, stream>>>(qh, kth, Pb);   // probe
  pv_kernel<<<dim3(128), 256, 0, stream>>>(Pb, vtb, yb);
  pv_kernel<<<dim3(128), 256, 0, stream>>>(Pb, vtb, yb);       // probe
  out_mfma32_kernel<<<dim3(16, 16), 256, 0, stream>>>(yb, Wto, out);
}

// Round 19
// 55.884 us; speedup vs baseline: 1.5099x; 1.5099x over previous
//
#include <hip/hip_runtime.h>
#include <hip/hip_bf16.h>
#include <math.h>

#define TT 512
#define CC 1024
#define NH 16
#define NKV 8
#define HD 64
static constexpr float EPS_ = 1e-6f;

typedef short bf16x8 __attribute__((ext_vector_type(8)));
typedef float f32x4 __attribute__((ext_vector_type(4)));
typedef _Float16 half2v __attribute__((ext_vector_type(2)));

__device__ __forceinline__ ushort f2bf(float f) {
  union { __hip_bfloat16 h; ushort u; } cv;
  cv.h = __float2bfloat16(f);
  return cv.u;
}
__device__ __forceinline__ ushort f2h(float f) {
  union { _Float16 h; ushort u; } cv;
  cv.h = (_Float16)f;
  return cv.u;
}
__device__ __forceinline__ half2v bch2(uint u) {
  union { uint u; half2v h; } cv;
  cv.u = u;
  return cv.h;
}

// ---------------------------------------------------------------------------
// prep: x -> bf16 (same layout); Wq/Wk/Wv/Wo -> transposed bf16 Wt[n][k]
// ---------------------------------------------------------------------------
__global__ __launch_bounds__(256) void prep_kernel(
    const float* __restrict__ x,
    const float* __restrict__ Wq, const float* __restrict__ Wk,
    const float* __restrict__ Wv, const float* __restrict__ Wo,
    ushort* __restrict__ xb, ushort* __restrict__ Wtq, ushort* __restrict__ Wtk,
    ushort* __restrict__ Wtv, ushort* __restrict__ Wto)
{
  int b = blockIdx.x;
  if (b < 256) {
    int base = b * 2048 + threadIdx.x * 8;
    float4 f0 = *reinterpret_cast<const float4*>(&x[base]);
    float4 f1 = *reinterpret_cast<const float4*>(&x[base + 4]);
    union { ushort u[8]; uint4 v; } pk;
    pk.u[0] = f2bf(f0.x); pk.u[1] = f2bf(f0.y); pk.u[2] = f2bf(f0.z); pk.u[3] = f2bf(f0.w);
    pk.u[4] = f2bf(f1.x); pk.u[5] = f2bf(f1.y); pk.u[6] = f2bf(f1.z); pk.u[7] = f2bf(f1.w);
    *reinterpret_cast<uint4*>(&xb[base]) = pk.v;
    return;
  }
  b -= 256;
  const float* W; ushort* Wt; int ldW, tr, tc;
  if (b < 256)      { W = Wq; Wt = Wtq; ldW = 1024; tr = b >> 4;       tc = b & 15; }
  else if (b < 384) { int q = b - 256; W = Wk; Wt = Wtk; ldW = 512; tr = q >> 3; tc = q & 7; }
  else if (b < 512) { int q = b - 384; W = Wv; Wt = Wtv; ldW = 512; tr = q >> 3; tc = q & 7; }
  else              { int q = b - 512; W = Wo; Wt = Wto; ldW = 1024; tr = q >> 4; tc = q & 15; }
  const int k0 = tr * 64, n0 = tc * 64;
  __shared__ float ft[64][65];
  const int t = threadIdx.x;
#pragma unroll
  for (int it = 0; it < 4; ++it) {
    int q = t + it * 256;
    int r = q >> 4, c4 = q & 15;
    float4 f = *reinterpret_cast<const float4*>(&W[(k0 + r) * ldW + n0 + c4 * 4]);
    ft[r][c4 * 4 + 0] = f.x; ft[r][c4 * 4 + 1] = f.y;
    ft[r][c4 * 4 + 2] = f.z; ft[r][c4 * 4 + 3] = f.w;
  }
  __syncthreads();
#pragma unroll
  for (int it = 0; it < 2; ++it) {
    int q = t + it * 256;
    int n = q >> 3, kc = q & 7;
    union { ushort u[8]; uint4 v; } pk;
#pragma unroll
    for (int j = 0; j < 8; ++j) pk.u[j] = f2bf(ft[kc * 8 + j][n]);
    *reinterpret_cast<uint4*>(&Wt[(n0 + n) * 1024 + k0 + kc * 8]) = pk.v;
  }
}

// ---------------------------------------------------------------------------
// Fused QKV GEMM + rope/rms/pack epilogue. 32x64 tiles, grid (32,16) = 512
// blocks (2/CU), full K=1024. Each block owns complete head-rows, so the
// epilogue is entirely block-local (no cross-block sync — R16 lesson).
//   bx<16:  q: head h=bx, t-rows by*32 -> rope+rms -> packed half2 qh
//   bx<24:  k: g=bx-16             -> rope+rms -> packed half2 K^T kth
//   else:   v: g=bx-24             -> bf16 V^T vt
// ---------------------------------------------------------------------------
__global__ __launch_bounds__(256) void qkv_rope_kernel(
    const ushort* __restrict__ xb,
    const ushort* __restrict__ Wtq, const ushort* __restrict__ Wtk, const ushort* __restrict__ Wtv,
    const float* __restrict__ cosb, const float* __restrict__ sinb,
    uint* __restrict__ qh, uint* __restrict__ kth, ushort* __restrict__ vt)
{
  __shared__ ushort At[32][72];
  __shared__ ushort Bs[64][72];
  __shared__ float ft[32][65];
  const int tid = threadIdx.x;
  const int lane = tid & 63, w = tid >> 6;
  const int bx = blockIdx.x, by = blockIdx.y;
  const int row0 = by * 32;

  const ushort* Bt; int col0;
  if (bx < 16)      { Bt = Wtq; col0 = bx * 64; }
  else if (bx < 24) { Bt = Wtk; col0 = (bx - 16) * 64; }
  else              { Bt = Wtv; col0 = (bx - 24) * 64; }

  const int m0 = (w & 1) * 16, n0 = (w >> 1) * 32;
  const int lr = lane & 15, lk = (lane >> 4) * 8;
  f32x4 acc[2] = {};
  const int srA = tid >> 3, scA = (tid & 7) * 8;
  const int srB = tid >> 2, scB = (tid & 3) * 16;
  const ushort* Ap = &xb[(row0 + srA) * 1024 + scA];
  const ushort* Bp = &Bt[(col0 + srB) * 1024 + scB];

  for (int k0 = 0; k0 < 1024; k0 += 64) {
    __syncthreads();
    uint4 a0 = *reinterpret_cast<const uint4*>(Ap + k0);
    uint4 b0 = *reinterpret_cast<const uint4*>(Bp + k0);
    uint4 b1 = *reinterpret_cast<const uint4*>(Bp + k0 + 8);
    *reinterpret_cast<uint4*>(&At[srA][scA]) = a0;
    *reinterpret_cast<uint4*>(&Bs[srB][scB]) = b0;
    *reinterpret_cast<uint4*>(&Bs[srB][scB + 8]) = b1;
    __syncthreads();
#pragma unroll
    for (int kk = 0; kk < 2; ++kk) {
      bf16x8 af = *reinterpret_cast<const bf16x8*>(&At[m0 + lr][kk * 32 + lk]);
#pragma unroll
      for (int ni = 0; ni < 2; ++ni) {
        bf16x8 bg = *reinterpret_cast<const bf16x8*>(&Bs[n0 + ni * 16 + lr][kk * 32 + lk]);
        acc[ni] = __builtin_amdgcn_mfma_f32_16x16x32_bf16(af, bg, acc[ni], 0, 0, 0);
      }
    }
  }

  // acc -> ft (fp32 result tile, 32 rows x 64 cols)
  const int crow = (lane >> 4) * 4, ccol = lane & 15;
  __syncthreads();                       // staging LDS fully consumed
#pragma unroll
  for (int ni = 0; ni < 2; ++ni)
#pragma unroll
    for (int r = 0; r < 4; ++r)
      ft[m0 + crow + r][n0 + ni * 16 + ccol] = acc[ni][r];
  __syncthreads();

  if (bx < 16) {                         // ---- q: rope+rms -> packed half2 qh
    const int h = bx;
#pragma unroll 2
    for (int rr = 0; rr < 8; ++rr) {
      int row = w * 8 + rr;
      int t = row0 + row;
      float vv = ft[row][lane];
      float pt = ft[row][lane ^ 32];
      int f = lane & 31;
      float c = cosb[t * 32 + f], s = sinb[t * 32 + f];
      float o = (lane < 32) ? (vv * c - pt * s) : (pt * s + vv * c);
      float ss = o * o;
#pragma unroll
      for (int off = 32; off; off >>= 1) ss += __shfl_xor(ss, off);
      float rN = rsqrtf(ss * (1.0f / 64.0f) + EPS_);
      uint hv = (uint)f2h(o * rN);
      uint nb = __shfl_down(hv, 1);
      if ((lane & 1) == 0)
        qh[(t * 16 + h) * 32 + (lane >> 1)] = hv | (nb << 16);
    }
    return;
  }
  if (bx < 24) {                         // ---- k: rope+rms -> packed half2 K^T
    const int g = bx - 16;
#pragma unroll 2
    for (int rr = 0; rr < 8; ++rr) {
      int row = w * 8 + rr;
      int t = row0 + row;
      float vv = ft[row][lane];
      float pt = ft[row][lane ^ 32];    // wave-synchronous: reads precede write
      int f = lane & 31;
      float c = cosb[t * 32 + f], s = sinb[t * 32 + f];
      float o = (lane < 32) ? (vv * c - pt * s) : (pt * s + vv * c);
      float ss = o * o;
#pragma unroll
      for (int off = 32; off; off >>= 1) ss += __shfl_xor(ss, off);
      ft[row][lane] = o * rsqrtf(ss * (1.0f / 64.0f) + EPS_);
    }
    __syncthreads();
#pragma unroll
    for (int it = 0; it < 4; ++it) {
      int idx2 = tid + it * 256;         // 0..1023
      int d2 = idx2 >> 5, tt = idx2 & 31;
      uint lo = (uint)f2h(ft[tt][2 * d2]);
      uint hi = (uint)f2h(ft[tt][2 * d2 + 1]);
      kth[g * 16384 + d2 * 512 + row0 + tt] = lo | (hi << 16);
    }
    return;
  }
  // ---- v: convert + transpose -> vt (bf16)
  const int g = bx - 24;
#pragma unroll
  for (int it = 0; it < 4; ++it) {
    int idx2 = tid + it * 256;           // 0..1023
    int d = idx2 >> 4, tp = idx2 & 15;   // d 0..63, t-pair 0..15
    uint o = (uint)f2bf(ft[tp * 2][d]) | ((uint)f2bf(ft[tp * 2 + 1][d]) << 16);
    *reinterpret_cast<uint*>(&vt[g * 32768 + d * 512 + row0 + tp * 2]) = o;
  }
}

// ---------------------------------------------------------------------------
// out GEMM, 32x64 tiles: grid (16,16) = 256 blocks (1/CU). (R17-proven)
// ---------------------------------------------------------------------------
__global__ __launch_bounds__(256) void out_mfma32_kernel(
    const ushort* __restrict__ yb, const ushort* __restrict__ Wto, float* __restrict__ out)
{
  __shared__ ushort At[32][72];
  __shared__ ushort Bs[64][72];
  const int tid = threadIdx.x;
  const int lane = tid & 63, w = tid >> 6;
  const int row0 = blockIdx.y * 32, col0 = blockIdx.x * 64;
  const int m0 = (w & 1) * 16, n0 = (w >> 1) * 32;
  const int lr = lane & 15, lk = (lane >> 4) * 8;
  f32x4 acc[2] = {};
  const int srA = tid >> 3, scA = (tid & 7) * 8;
  const int srB = tid >> 2, scB = (tid & 3) * 16;
  const ushort* Ap = &yb[(row0 + srA) * 1024 + scA];
  const ushort* Bp = &Wto[(col0 + srB) * 1024 + scB];

  for (int k0 = 0; k0 < 1024; k0 += 64) {
    __syncthreads();
    uint4 a0 = *reinterpret_cast<const uint4*>(Ap + k0);
    uint4 b0 = *reinterpret_cast<const uint4*>(Bp + k0);
    uint4 b1 = *reinterpret_cast<const uint4*>(Bp + k0 + 8);
    *reinterpret_cast<uint4*>(&At[srA][scA]) = a0;
    *reinterpret_cast<uint4*>(&Bs[srB][scB]) = b0;
    *reinterpret_cast<uint4*>(&Bs[srB][scB + 8]) = b1;
    __syncthreads();
#pragma unroll
    for (int kk = 0; kk < 2; ++kk) {
      bf16x8 af = *reinterpret_cast<const bf16x8*>(&At[m0 + lr][kk * 32 + lk]);
#pragma unroll
      for (int ni = 0; ni < 2; ++ni) {
        bf16x8 bg = *reinterpret_cast<const bf16x8*>(&Bs[n0 + ni * 16 + lr][kk * 32 + lk]);
        acc[ni] = __builtin_amdgcn_mfma_f32_16x16x32_bf16(af, bg, acc[ni], 0, 0, 0);
      }
    }
  }
  const int crow = (lane >> 4) * 4, ccol = lane & 15;
#pragma unroll
  for (int ni = 0; ni < 2; ++ni)
#pragma unroll
    for (int r = 0; r < 4; ++r)
      out[(row0 + m0 + crow + r) * 1024 + col0 + n0 + ni * 16 + ccol] = acc[ni][r];
}

// ---------------------------------------------------------------------------
// Phase A v3: tropical scores via packed fp16 (R15-proven).
// ---------------------------------------------------------------------------
__global__ __launch_bounds__(256) void score_kernel(
    const uint* __restrict__ qh, const uint* __restrict__ kth,
    ushort* __restrict__ Pb)
{
  const int tid = threadIdx.x;
  const int w = tid >> 6, lane = tid & 63;
  const int u = blockIdx.x * 4 + w;
  const int h = u / 576;
  const int r = u - h * 576;
  const int A = (r >= 16) + (r >= 48) + (r >= 96) + (r >= 160) +
                (r >= 240) + (r >= 336) + (r >= 448);
  const int rb = r - 8 * A * (A + 1);
  const int c4 = 16 * A + rb / (A + 1);
  const int jt = rb % (A + 1);
  const int g = h >> 1;
  const int i0 = c4 * 4;
  const int j0 = jt * 64;
  const bool diag = (jt == A);

  half2v kreg[32];
  const uint* ktp = &kth[g * 16384 + j0 + lane];
#pragma unroll
  for (int d2 = 0; d2 < 32; ++d2) kreg[d2] = bch2(ktp[d2 * 512]);

  ushort* pp = &Pb[h * (TT * TT) + i0 * 512 + j0 + lane];
  const half2v NEGBIG = {(_Float16)-60000.0f, (_Float16)-60000.0f};

#pragma unroll 2
  for (int q = 0; q < 4; ++q) {
    const uint4* qp4 = reinterpret_cast<const uint4*>(&qh[((i0 + q) * 16 + h) * 32]);
    half2v m0 = NEGBIG, m1 = NEGBIG;
#pragma unroll
    for (int it = 0; it < 8; ++it) {
      uint4 qq = qp4[it];
      half2v a0 = bch2(qq.x) + kreg[it * 4 + 0];
      half2v a1 = bch2(qq.y) + kreg[it * 4 + 1];
      half2v a2 = bch2(qq.z) + kreg[it * 4 + 2];
      half2v a3 = bch2(qq.w) + kreg[it * 4 + 3];
      m0 = __builtin_elementwise_max(m0, __builtin_elementwise_max(a0, a1));
      m1 = __builtin_elementwise_max(m1, __builtin_elementwise_max(a2, a3));
    }
    half2v mm = __builtin_elementwise_max(m0, m1);
    float s = fmaxf((float)mm[0], (float)mm[1]);
    if (diag && (j0 + lane > i0 + q)) s = -INFINITY;
    pp[q * 512] = f2bf(__expf(s));
  }
}

// ---------------------------------------------------------------------------
// Phase B: y = (P @ V) / rowsum(P) via bf16 MFMA (R13-proven).
// ---------------------------------------------------------------------------
__global__ __launch_bounds__(256) void pv_kernel(
    const ushort* __restrict__ Pb, const ushort* __restrict__ vt,
    ushort* __restrict__ yb)
{
  __shared__ __align__(16) ushort Ps[64][72];
  __shared__ __align__(16) ushort Vs[64][72];
  const int tid = threadIdx.x;
  const int w = tid >> 6, lane = tid & 63;
  const int bx = blockIdx.x;
  const int h = bx & 15;
  const int cc = 7 - (bx >> 4);
  const int g = h >> 1;
  const int i0 = cc * 64;
  const int rbw = w * 16;
  const int lr = lane & 15, lk = (lane >> 4) * 8;
  f32x4 acc[4] = {};
  f32x4 accl = {};

  bf16x8 ones;
#pragma unroll
  for (int e = 0; e < 8; ++e) ones[e] = (short)0x3F80;

  const int srow = tid >> 2, scol = (tid & 3) * 16;
  for (int jt = 0; jt <= cc; ++jt) {
    const int j0 = jt * 64;
    __syncthreads();
    {
      const ushort* ps = &Pb[h * (TT * TT) + (i0 + srow) * 512 + j0 + scol];
      uint4 a0 = *reinterpret_cast<const uint4*>(ps);
      uint4 a1 = *reinterpret_cast<const uint4*>(ps + 8);
      const ushort* vs = &vt[g * 32768 + srow * 512 + j0 + scol];
      uint4 b0 = *reinterpret_cast<const uint4*>(vs);
      uint4 b1 = *reinterpret_cast<const uint4*>(vs + 8);
      *reinterpret_cast<uint4*>(&Ps[srow][scol]) = a0;
      *reinterpret_cast<uint4*>(&Ps[srow][scol + 8]) = a1;
      *reinterpret_cast<uint4*>(&Vs[srow][scol]) = b0;
      *reinterpret_cast<uint4*>(&Vs[srow][scol + 8]) = b1;
    }
    __syncthreads();
#pragma unroll
    for (int kk = 0; kk < 2; ++kk) {
      bf16x8 af = *reinterpret_cast<const bf16x8*>(&Ps[rbw + lr][kk * 32 + lk]);
      accl = __builtin_amdgcn_mfma_f32_16x16x32_bf16(af, ones, accl, 0, 0, 0);
#pragma unroll
      for (int ni = 0; ni < 4; ++ni) {
        bf16x8 bg = *reinterpret_cast<const bf16x8*>(&Vs[ni * 16 + lr][kk * 32 + lk]);
        acc[ni] = __builtin_amdgcn_mfma_f32_16x16x32_bf16(af, bg, acc[ni], 0, 0, 0);
      }
    }
  }

  const int crow = (lane >> 4) * 4, ccol = lane & 15;
#pragma unroll
  for (int r = 0; r < 4; ++r) {
    int i = i0 + rbw + crow + r;
    float linv = 1.0f / accl[r];
#pragma unroll
    for (int ni = 0; ni < 4; ++ni)
      yb[i * 1024 + h * 64 + ni * 16 + ccol] = f2bf(acc[ni][r] * linv);
  }
}

// ---------------------------------------------------------------------------
extern "C" void kernel_launch(void* const* d_in, const int* in_sizes, int n_in,
                              void* d_out, int out_size, void* d_ws, size_t ws_size,
                              hipStream_t stream) {
  const float* x    = (const float*)d_in[0];
  const float* cosb = (const float*)d_in[1];
  const float* sinb = (const float*)d_in[2];
  const float* Wq   = (const float*)d_in[3];
  const float* Wk   = (const float*)d_in[4];
  const float* Wv   = (const float*)d_in[5];
  const float* Wo   = (const float*)d_in[6];
  float* out = (float*)d_out;

  uint* wsu32 = (uint*)d_ws;
  uint*  kth  = wsu32;                     // 8x32x512 uint (half2 K^T)
  uint*  qh   = kth + 8 * 32 * 512;        // 512x16x32 uint (half2 q)
  ushort* xb  = (ushort*)(qh + TT * 16 * 32);  // 512x1024 bf16
  ushort* yb  = xb + TT * CC;              // 512x1024 bf16
  ushort* Pb  = yb + TT * CC;              // 16x512x512 bf16 (P matrix)
  ushort* vtb = Pb + NH * TT * TT;         // 8x64x512 bf16 (V^T)
  ushort* Wtq = vtb + 8 * 64 * 512;        // 1024x1024 bf16
  ushort* Wtk = Wtq + CC * CC;             // 512x1024 bf16
  ushort* Wtv = Wtk + 512 * CC;            // 512x1024 bf16
  ushort* Wto = Wtv + 512 * CC;            // 1024x1024 bf16

  prep_kernel<<<dim3(1024), 256, 0, stream>>>(x, Wq, Wk, Wv, Wo, xb, Wtq, Wtk, Wtv, Wto);
  qkv_rope_kernel<<<dim3(32, 16), 256, 0, stream>>>(
      xb, Wtq, Wtk, Wtv, cosb, sinb, qh, kth, vtb);
  score_kernel<<<dim3(2304), 256, 0, stream>>>(qh, kth, Pb);
  pv_kernel<<<dim3(128), 256, 0, stream>>>(Pb, vtb, yb);
  out_mfma32_kernel<<<dim3(16, 16), 256, 0, stream>>>(yb, Wto, out);
}

// Round 20
// 52.149 us; speedup vs baseline: 1.6181x; 1.0716x over previous
//
#include <hip/hip_runtime.h>
#include <hip/hip_bf16.h>
#include <math.h>

#define TT 512
#define CC 1024
#define NH 16
#define NKV 8
#define HD 64
static constexpr float EPS_ = 1e-6f;

typedef short bf16x8 __attribute__((ext_vector_type(8)));
typedef float f32x4 __attribute__((ext_vector_type(4)));
typedef _Float16 half2v __attribute__((ext_vector_type(2)));

__device__ __forceinline__ ushort f2bf(float f) {
  union { __hip_bfloat16 h; ushort u; } cv;
  cv.h = __float2bfloat16(f);
  return cv.u;
}
__device__ __forceinline__ ushort f2h(float f) {
  union { _Float16 h; ushort u; } cv;
  cv.h = (_Float16)f;
  return cv.u;
}
__device__ __forceinline__ half2v bch2(uint u) {
  union { uint u; half2v h; } cv;
  cv.u = u;
  return cv.h;
}

// ---------------------------------------------------------------------------
// prep: x -> bf16 (same layout); Wq/Wk/Wv/Wo -> transposed bf16 Wt[n][k]
// ---------------------------------------------------------------------------
__global__ __launch_bounds__(256) void prep_kernel(
    const float* __restrict__ x,
    const float* __restrict__ Wq, const float* __restrict__ Wk,
    const float* __restrict__ Wv, const float* __restrict__ Wo,
    ushort* __restrict__ xb, ushort* __restrict__ Wtq, ushort* __restrict__ Wtk,
    ushort* __restrict__ Wtv, ushort* __restrict__ Wto)
{
  int b = blockIdx.x;
  if (b < 256) {
    int base = b * 2048 + threadIdx.x * 8;
    float4 f0 = *reinterpret_cast<const float4*>(&x[base]);
    float4 f1 = *reinterpret_cast<const float4*>(&x[base + 4]);
    union { ushort u[8]; uint4 v; } pk;
    pk.u[0] = f2bf(f0.x); pk.u[1] = f2bf(f0.y); pk.u[2] = f2bf(f0.z); pk.u[3] = f2bf(f0.w);
    pk.u[4] = f2bf(f1.x); pk.u[5] = f2bf(f1.y); pk.u[6] = f2bf(f1.z); pk.u[7] = f2bf(f1.w);
    *reinterpret_cast<uint4*>(&xb[base]) = pk.v;
    return;
  }
  b -= 256;
  const float* W; ushort* Wt; int ldW, tr, tc;
  if (b < 256)      { W = Wq; Wt = Wtq; ldW = 1024; tr = b >> 4;       tc = b & 15; }
  else if (b < 384) { int q = b - 256; W = Wk; Wt = Wtk; ldW = 512; tr = q >> 3; tc = q & 7; }
  else if (b < 512) { int q = b - 384; W = Wv; Wt = Wtv; ldW = 512; tr = q >> 3; tc = q & 7; }
  else              { int q = b - 512; W = Wo; Wt = Wto; ldW = 1024; tr = q >> 4; tc = q & 15; }
  const int k0 = tr * 64, n0 = tc * 64;
  __shared__ float ft[64][65];
  const int t = threadIdx.x;
#pragma unroll
  for (int it = 0; it < 4; ++it) {
    int q = t + it * 256;
    int r = q >> 4, c4 = q & 15;
    float4 f = *reinterpret_cast<const float4*>(&W[(k0 + r) * ldW + n0 + c4 * 4]);
    ft[r][c4 * 4 + 0] = f.x; ft[r][c4 * 4 + 1] = f.y;
    ft[r][c4 * 4 + 2] = f.z; ft[r][c4 * 4 + 3] = f.w;
  }
  __syncthreads();
#pragma unroll
  for (int it = 0; it < 2; ++it) {
    int q = t + it * 256;
    int n = q >> 3, kc = q & 7;
    union { ushort u[8]; uint4 v; } pk;
#pragma unroll
    for (int j = 0; j < 8; ++j) pk.u[j] = f2bf(ft[kc * 8 + j][n]);
    *reinterpret_cast<uint4*>(&Wt[(n0 + n) * 1024 + k0 + kc * 8]) = pk.v;
  }
}

// ---------------------------------------------------------------------------
// Fused QKV GEMM + rope/rms/pack epilogue (R19-proven). 32x64 tiles,
// grid (32,16) = 512 blocks.
// ---------------------------------------------------------------------------
__global__ __launch_bounds__(256) void qkv_rope_kernel(
    const ushort* __restrict__ xb,
    const ushort* __restrict__ Wtq, const ushort* __restrict__ Wtk, const ushort* __restrict__ Wtv,
    const float* __restrict__ cosb, const float* __restrict__ sinb,
    uint* __restrict__ qh, uint* __restrict__ kth, ushort* __restrict__ vt)
{
  __shared__ ushort At[32][72];
  __shared__ ushort Bs[64][72];
  __shared__ float ft[32][65];
  const int tid = threadIdx.x;
  const int lane = tid & 63, w = tid >> 6;
  const int bx = blockIdx.x, by = blockIdx.y;
  const int row0 = by * 32;

  const ushort* Bt; int col0;
  if (bx < 16)      { Bt = Wtq; col0 = bx * 64; }
  else if (bx < 24) { Bt = Wtk; col0 = (bx - 16) * 64; }
  else              { Bt = Wtv; col0 = (bx - 24) * 64; }

  const int m0 = (w & 1) * 16, n0 = (w >> 1) * 32;
  const int lr = lane & 15, lk = (lane >> 4) * 8;
  f32x4 acc[2] = {};
  const int srA = tid >> 3, scA = (tid & 7) * 8;
  const int srB = tid >> 2, scB = (tid & 3) * 16;
  const ushort* Ap = &xb[(row0 + srA) * 1024 + scA];
  const ushort* Bp = &Bt[(col0 + srB) * 1024 + scB];

  for (int k0 = 0; k0 < 1024; k0 += 64) {
    __syncthreads();
    uint4 a0 = *reinterpret_cast<const uint4*>(Ap + k0);
    uint4 b0 = *reinterpret_cast<const uint4*>(Bp + k0);
    uint4 b1 = *reinterpret_cast<const uint4*>(Bp + k0 + 8);
    *reinterpret_cast<uint4*>(&At[srA][scA]) = a0;
    *reinterpret_cast<uint4*>(&Bs[srB][scB]) = b0;
    *reinterpret_cast<uint4*>(&Bs[srB][scB + 8]) = b1;
    __syncthreads();
#pragma unroll
    for (int kk = 0; kk < 2; ++kk) {
      bf16x8 af = *reinterpret_cast<const bf16x8*>(&At[m0 + lr][kk * 32 + lk]);
#pragma unroll
      for (int ni = 0; ni < 2; ++ni) {
        bf16x8 bg = *reinterpret_cast<const bf16x8*>(&Bs[n0 + ni * 16 + lr][kk * 32 + lk]);
        acc[ni] = __builtin_amdgcn_mfma_f32_16x16x32_bf16(af, bg, acc[ni], 0, 0, 0);
      }
    }
  }

  const int crow = (lane >> 4) * 4, ccol = lane & 15;
  __syncthreads();
#pragma unroll
  for (int ni = 0; ni < 2; ++ni)
#pragma unroll
    for (int r = 0; r < 4; ++r)
      ft[m0 + crow + r][n0 + ni * 16 + ccol] = acc[ni][r];
  __syncthreads();

  if (bx < 16) {                         // q: rope+rms -> packed half2 qh
    const int h = bx;
#pragma unroll 2
    for (int rr = 0; rr < 8; ++rr) {
      int row = w * 8 + rr;
      int t = row0 + row;
      float vv = ft[row][lane];
      float pt = ft[row][lane ^ 32];
      int f = lane & 31;
      float c = cosb[t * 32 + f], s = sinb[t * 32 + f];
      float o = (lane < 32) ? (vv * c - pt * s) : (pt * s + vv * c);
      float ss = o * o;
#pragma unroll
      for (int off = 32; off; off >>= 1) ss += __shfl_xor(ss, off);
      float rN = rsqrtf(ss * (1.0f / 64.0f) + EPS_);
      uint hv = (uint)f2h(o * rN);
      uint nb = __shfl_down(hv, 1);
      if ((lane & 1) == 0)
        qh[(t * 16 + h) * 32 + (lane >> 1)] = hv | (nb << 16);
    }
    return;
  }
  if (bx < 24) {                         // k: rope+rms -> packed half2 K^T
    const int g = bx - 16;
#pragma unroll 2
    for (int rr = 0; rr < 8; ++rr) {
      int row = w * 8 + rr;
      int t = row0 + row;
      float vv = ft[row][lane];
      float pt = ft[row][lane ^ 32];
      int f = lane & 31;
      float c = cosb[t * 32 + f], s = sinb[t * 32 + f];
      float o = (lane < 32) ? (vv * c - pt * s) : (pt * s + vv * c);
      float ss = o * o;
#pragma unroll
      for (int off = 32; off; off >>= 1) ss += __shfl_xor(ss, off);
      ft[row][lane] = o * rsqrtf(ss * (1.0f / 64.0f) + EPS_);
    }
    __syncthreads();
#pragma unroll
    for (int it = 0; it < 4; ++it) {
      int idx2 = tid + it * 256;
      int d2 = idx2 >> 5, tt = idx2 & 31;
      uint lo = (uint)f2h(ft[tt][2 * d2]);
      uint hi = (uint)f2h(ft[tt][2 * d2 + 1]);
      kth[g * 16384 + d2 * 512 + row0 + tt] = lo | (hi << 16);
    }
    return;
  }
  // v: convert + transpose -> vt (bf16)
  const int g = bx - 24;
#pragma unroll
  for (int it = 0; it < 4; ++it) {
    int idx2 = tid + it * 256;
    int d = idx2 >> 4, tp = idx2 & 15;
    uint o = (uint)f2bf(ft[tp * 2][d]) | ((uint)f2bf(ft[tp * 2 + 1][d]) << 16);
    *reinterpret_cast<uint*>(&vt[g * 32768 + d * 512 + row0 + tp * 2]) = o;
  }
}

// ---------------------------------------------------------------------------
// out GEMM, 32x64 tiles (R17-proven).
// ---------------------------------------------------------------------------
__global__ __launch_bounds__(256) void out_mfma32_kernel(
    const ushort* __restrict__ yb, const ushort* __restrict__ Wto, float* __restrict__ out)
{
  __shared__ ushort At[32][72];
  __shared__ ushort Bs[64][72];
  const int tid = threadIdx.x;
  const int lane = tid & 63, w = tid >> 6;
  const int row0 = blockIdx.y * 32, col0 = blockIdx.x * 64;
  const int m0 = (w & 1) * 16, n0 = (w >> 1) * 32;
  const int lr = lane & 15, lk = (lane >> 4) * 8;
  f32x4 acc[2] = {};
  const int srA = tid >> 3, scA = (tid & 7) * 8;
  const int srB = tid >> 2, scB = (tid & 3) * 16;
  const ushort* Ap = &yb[(row0 + srA) * 1024 + scA];
  const ushort* Bp = &Wto[(col0 + srB) * 1024 + scB];

  for (int k0 = 0; k0 < 1024; k0 += 64) {
    __syncthreads();
    uint4 a0 = *reinterpret_cast<const uint4*>(Ap + k0);
    uint4 b0 = *reinterpret_cast<const uint4*>(Bp + k0);
    uint4 b1 = *reinterpret_cast<const uint4*>(Bp + k0 + 8);
    *reinterpret_cast<uint4*>(&At[srA][scA]) = a0;
    *reinterpret_cast<uint4*>(&Bs[srB][scB]) = b0;
    *reinterpret_cast<uint4*>(&Bs[srB][scB + 8]) = b1;
    __syncthreads();
#pragma unroll
    for (int kk = 0; kk < 2; ++kk) {
      bf16x8 af = *reinterpret_cast<const bf16x8*>(&At[m0 + lr][kk * 32 + lk]);
#pragma unroll
      for (int ni = 0; ni < 2; ++ni) {
        bf16x8 bg = *reinterpret_cast<const bf16x8*>(&Bs[n0 + ni * 16 + lr][kk * 32 + lk]);
        acc[ni] = __builtin_amdgcn_mfma_f32_16x16x32_bf16(af, bg, acc[ni], 0, 0, 0);
      }
    }
  }
  const int crow = (lane >> 4) * 4, ccol = lane & 15;
#pragma unroll
  for (int ni = 0; ni < 2; ++ni)
#pragma unroll
    for (int r = 0; r < 4; ++r)
      out[(row0 + m0 + crow + r) * 1024 + col0 + n0 + ni * 16 + ccol] = acc[ni][r];
}

// ---------------------------------------------------------------------------
// Fused attention: score (packed fp16, P -> LDS) + PV (bf16 MFMA) in ONE
// kernel, block-local (no cross-block flow — R16 lesson). Block = (head h,
// 32-row i-chunk): 256 blocks x 512 thr (8 waves). Phase 1: wave w computes
// rows i0+4w..+3 over all causal j-tiles into Ps (pad 520 -> 2-way, free).
// One barrier. Phase 2: per j-tile stage V [64][72], MFMA P x V + ones-MFMA
// rowsum, divide, write y. P values bit-identical to the split version.
// ---------------------------------------------------------------------------
__global__ __launch_bounds__(512) void attn_fused_kernel(
    const uint* __restrict__ qh, const uint* __restrict__ kth,
    const ushort* __restrict__ vt, ushort* __restrict__ yb)
{
  __shared__ __align__(16) ushort Ps[32][520];   // 33,280 B
  __shared__ __align__(16) ushort Vt[64][72];    //  9,216 B  (total 42.5 KB)
  const int tid = threadIdx.x;
  const int w = tid >> 6, lane = tid & 63;
  const int bx = blockIdx.x;
  const int h = bx & 15;
  const int ic = 15 - (bx >> 4);        // heavy chunks first
  const int g = h >> 1;
  const int i0 = ic * 32;
  const int njt = ((i0 + 31) >> 6) + 1; // causal j-tiles of 64

  // ---- phase 1: scores + exp -> Ps (each wave: 4 rows, all j-tiles)
  const half2v NEGBIG = {(_Float16)-60000.0f, (_Float16)-60000.0f};
  for (int jt = 0; jt < njt; ++jt) {
    const int j0 = jt * 64;
    const bool diag = (jt == njt - 1);
    half2v kreg[32];
    const uint* ktp = &kth[g * 16384 + j0 + lane];
#pragma unroll
    for (int d2 = 0; d2 < 32; ++d2) kreg[d2] = bch2(ktp[d2 * 512]);
#pragma unroll
    for (int q = 0; q < 4; ++q) {
      const int lrow = w * 4 + q;        // local row 0..31
      const int row = i0 + lrow;
      const uint4* qp4 = reinterpret_cast<const uint4*>(&qh[(row * 16 + h) * 32]);
      half2v m0 = NEGBIG, m1 = NEGBIG;
#pragma unroll
      for (int it = 0; it < 8; ++it) {
        uint4 qq = qp4[it];
        half2v a0 = bch2(qq.x) + kreg[it * 4 + 0];
        half2v a1 = bch2(qq.y) + kreg[it * 4 + 1];
        half2v a2 = bch2(qq.z) + kreg[it * 4 + 2];
        half2v a3 = bch2(qq.w) + kreg[it * 4 + 3];
        m0 = __builtin_elementwise_max(m0, __builtin_elementwise_max(a0, a1));
        m1 = __builtin_elementwise_max(m1, __builtin_elementwise_max(a2, a3));
      }
      half2v mm = __builtin_elementwise_max(m0, m1);
      float s = fmaxf((float)mm[0], (float)mm[1]);
      if (diag && (j0 + lane > row)) s = -INFINITY;
      Ps[lrow][j0 + lane] = f2bf(__expf(s));   // masked: exp(-inf)=0
    }
  }

  // ---- phase 2: y = (P @ V) / rowsum(P); V staged per j-tile
  const int m0r = (w & 1) * 16, n0c = (w >> 1) * 16;   // 2x4 tile grid
  const int lr = lane & 15, lk8 = (lane >> 4) * 8;
  f32x4 acc = {}, accl = {};
  bf16x8 ones;
#pragma unroll
  for (int e = 0; e < 8; ++e) ones[e] = (short)0x3F80;
  const int srow = tid >> 3, scol = (tid & 7) * 8;     // 64 x 64 staging

  for (int jt = 0; jt < njt; ++jt) {
    __syncthreads();                    // jt=0: also the phase-1/2 barrier
    *reinterpret_cast<uint4*>(&Vt[srow][scol]) =
        *reinterpret_cast<const uint4*>(&vt[g * 32768 + srow * 512 + jt * 64 + scol]);
    __syncthreads();
#pragma unroll
    for (int kk = 0; kk < 2; ++kk) {
      bf16x8 af = *reinterpret_cast<const bf16x8*>(&Ps[m0r + lr][jt * 64 + kk * 32 + lk8]);
      bf16x8 bg = *reinterpret_cast<const bf16x8*>(&Vt[n0c + lr][kk * 32 + lk8]);
      acc  = __builtin_amdgcn_mfma_f32_16x16x32_bf16(af, bg, acc, 0, 0, 0);
      accl = __builtin_amdgcn_mfma_f32_16x16x32_bf16(af, ones, accl, 0, 0, 0);
    }
  }

  const int crow = (lane >> 4) * 4, ccol = lane & 15;
#pragma unroll
  for (int r = 0; r < 4; ++r) {
    int i = i0 + m0r + crow + r;
    yb[i * 1024 + h * 64 + n0c + ccol] = f2bf(acc[r] / accl[r]);
  }
}

// ---------------------------------------------------------------------------
extern "C" void kernel_launch(void* const* d_in, const int* in_sizes, int n_in,
                              void* d_out, int out_size, void* d_ws, size_t ws_size,
                              hipStream_t stream) {
  const float* x    = (const float*)d_in[0];
  const float* cosb = (const float*)d_in[1];
  const float* sinb = (const float*)d_in[2];
  const float* Wq   = (const float*)d_in[3];
  const float* Wk   = (const float*)d_in[4];
  const float* Wv   = (const float*)d_in[5];
  const float* Wo   = (const float*)d_in[6];
  float* out = (float*)d_out;

  uint* wsu32 = (uint*)d_ws;
  uint*  kth  = wsu32;                     // 8x32x512 uint (half2 K^T)
  uint*  qh   = kth + 8 * 32 * 512;        // 512x16x32 uint (half2 q)
  ushort* xb  = (ushort*)(qh + TT * 16 * 32);  // 512x1024 bf16
  ushort* yb  = xb + TT * CC;              // 512x1024 bf16
  ushort* vtb = yb + TT * CC;              // 8x64x512 bf16 (V^T)
  ushort* Wtq = vtb + 8 * 64 * 512;        // 1024x1024 bf16
  ushort* Wtk = Wtq + CC * CC;             // 512x1024 bf16
  ushort* Wtv = Wtk + 512 * CC;            // 512x1024 bf16
  ushort* Wto = Wtv + 512 * CC;            // 1024x1024 bf16

  prep_kernel<<<dim3(1024), 256, 0, stream>>>(x, Wq, Wk, Wv, Wo, xb, Wtq, Wtk, Wtv, Wto);
  qkv_rope_kernel<<<dim3(32, 16), 256, 0, stream>>>(
      xb, Wtq, Wtk, Wtv, cosb, sinb, qh, kth, vtb);
  attn_fused_kernel<<<dim3(256), 512, 0, stream>>>(qh, kth, vtb, yb);
  out_mfma32_kernel<<<dim3(16, 16), 256, 0, stream>>>(yb, Wto, out);
}

// Round 21
// 46.338 us; speedup vs baseline: 1.8210x; 1.1254x over previous
//
#include <hip/hip_runtime.h>
#include <hip/hip_bf16.h>
#include <math.h>

#define TT 512
#define CC 1024
#define NH 16
#define NKV 8
#define HD 64
static constexpr float EPS_ = 1e-6f;

typedef short bf16x8 __attribute__((ext_vector_type(8)));
typedef float f32x4 __attribute__((ext_vector_type(4)));
typedef _Float16 half2v __attribute__((ext_vector_type(2)));

__device__ __forceinline__ ushort f2bf(float f) {
  union { __hip_bfloat16 h; ushort u; } cv;
  cv.h = __float2bfloat16(f);
  return cv.u;
}
__device__ __forceinline__ ushort f2h(float f) {
  union { _Float16 h; ushort u; } cv;
  cv.h = (_Float16)f;
  return cv.u;
}
__device__ __forceinline__ half2v bch2(uint u) {
  union { uint u; half2v h; } cv;
  cv.u = u;
  return cv.h;
}

// ---------------------------------------------------------------------------
// prep: x -> bf16 (same layout); Wq/Wk/Wv/Wo -> transposed bf16 Wt[n][k]
// ---------------------------------------------------------------------------
__global__ __launch_bounds__(256) void prep_kernel(
    const float* __restrict__ x,
    const float* __restrict__ Wq, const float* __restrict__ Wk,
    const float* __restrict__ Wv, const float* __restrict__ Wo,
    ushort* __restrict__ xb, ushort* __restrict__ Wtq, ushort* __restrict__ Wtk,
    ushort* __restrict__ Wtv, ushort* __restrict__ Wto)
{
  int b = blockIdx.x;
  if (b < 256) {
    int base = b * 2048 + threadIdx.x * 8;
    float4 f0 = *reinterpret_cast<const float4*>(&x[base]);
    float4 f1 = *reinterpret_cast<const float4*>(&x[base + 4]);
    union { ushort u[8]; uint4 v; } pk;
    pk.u[0] = f2bf(f0.x); pk.u[1] = f2bf(f0.y); pk.u[2] = f2bf(f0.z); pk.u[3] = f2bf(f0.w);
    pk.u[4] = f2bf(f1.x); pk.u[5] = f2bf(f1.y); pk.u[6] = f2bf(f1.z); pk.u[7] = f2bf(f1.w);
    *reinterpret_cast<uint4*>(&xb[base]) = pk.v;
    return;
  }
  b -= 256;
  const float* W; ushort* Wt; int ldW, tr, tc;
  if (b < 256)      { W = Wq; Wt = Wtq; ldW = 1024; tr = b >> 4;       tc = b & 15; }
  else if (b < 384) { int q = b - 256; W = Wk; Wt = Wtk; ldW = 512; tr = q >> 3; tc = q & 7; }
  else if (b < 512) { int q = b - 384; W = Wv; Wt = Wtv; ldW = 512; tr = q >> 3; tc = q & 7; }
  else              { int q = b - 512; W = Wo; Wt = Wto; ldW = 1024; tr = q >> 4; tc = q & 15; }
  const int k0 = tr * 64, n0 = tc * 64;
  __shared__ float ft[64][65];
  const int t = threadIdx.x;
#pragma unroll
  for (int it = 0; it < 4; ++it) {
    int q = t + it * 256;
    int r = q >> 4, c4 = q & 15;
    float4 f = *reinterpret_cast<const float4*>(&W[(k0 + r) * ldW + n0 + c4 * 4]);
    ft[r][c4 * 4 + 0] = f.x; ft[r][c4 * 4 + 1] = f.y;
    ft[r][c4 * 4 + 2] = f.z; ft[r][c4 * 4 + 3] = f.w;
  }
  __syncthreads();
#pragma unroll
  for (int it = 0; it < 2; ++it) {
    int q = t + it * 256;
    int n = q >> 3, kc = q & 7;
    union { ushort u[8]; uint4 v; } pk;
#pragma unroll
    for (int j = 0; j < 8; ++j) pk.u[j] = f2bf(ft[kc * 8 + j][n]);
    *reinterpret_cast<uint4*>(&Wt[(n0 + n) * 1024 + k0 + kc * 8]) = pk.v;
  }
}

// ---------------------------------------------------------------------------
// Fused QKV GEMM + rope/rms/pack epilogue. 32x64 tiles, grid (32,16) = 512
// blocks, BK=128 (8 K-steps, half the barriers of R19/R20's BK=64).
// ---------------------------------------------------------------------------
__global__ __launch_bounds__(256) void qkv_rope_kernel(
    const ushort* __restrict__ xb,
    const ushort* __restrict__ Wtq, const ushort* __restrict__ Wtk, const ushort* __restrict__ Wtv,
    const float* __restrict__ cosb, const float* __restrict__ sinb,
    uint* __restrict__ qh, uint* __restrict__ kth, ushort* __restrict__ vt)
{
  __shared__ ushort At[32][136];
  __shared__ ushort Bs[64][136];
  __shared__ float ft[32][65];
  const int tid = threadIdx.x;
  const int lane = tid & 63, w = tid >> 6;
  const int bx = blockIdx.x, by = blockIdx.y;
  const int row0 = by * 32;

  const ushort* Bt; int col0;
  if (bx < 16)      { Bt = Wtq; col0 = bx * 64; }
  else if (bx < 24) { Bt = Wtk; col0 = (bx - 16) * 64; }
  else              { Bt = Wtv; col0 = (bx - 24) * 64; }

  const int m0 = (w & 1) * 16, n0 = (w >> 1) * 32;
  const int lr = lane & 15, lk = (lane >> 4) * 8;
  f32x4 acc[2] = {};
  const int srA = tid >> 3, scA = (tid & 7) * 16;   // 32 rows x 128 k
  const int srB = tid >> 2, scB = (tid & 3) * 32;   // 64 rows x 128 k
  const ushort* Ap = &xb[(row0 + srA) * 1024 + scA];
  const ushort* Bp = &Bt[(col0 + srB) * 1024 + scB];

  for (int k0 = 0; k0 < 1024; k0 += 128) {
    __syncthreads();
    uint4 a0 = *reinterpret_cast<const uint4*>(Ap + k0);
    uint4 a1 = *reinterpret_cast<const uint4*>(Ap + k0 + 8);
    uint4 b0 = *reinterpret_cast<const uint4*>(Bp + k0);
    uint4 b1 = *reinterpret_cast<const uint4*>(Bp + k0 + 8);
    uint4 b2 = *reinterpret_cast<const uint4*>(Bp + k0 + 16);
    uint4 b3 = *reinterpret_cast<const uint4*>(Bp + k0 + 24);
    *reinterpret_cast<uint4*>(&At[srA][scA]) = a0;
    *reinterpret_cast<uint4*>(&At[srA][scA + 8]) = a1;
    *reinterpret_cast<uint4*>(&Bs[srB][scB]) = b0;
    *reinterpret_cast<uint4*>(&Bs[srB][scB + 8]) = b1;
    *reinterpret_cast<uint4*>(&Bs[srB][scB + 16]) = b2;
    *reinterpret_cast<uint4*>(&Bs[srB][scB + 24]) = b3;
    __syncthreads();
#pragma unroll
    for (int kk = 0; kk < 4; ++kk) {
      bf16x8 af = *reinterpret_cast<const bf16x8*>(&At[m0 + lr][kk * 32 + lk]);
#pragma unroll
      for (int ni = 0; ni < 2; ++ni) {
        bf16x8 bg = *reinterpret_cast<const bf16x8*>(&Bs[n0 + ni * 16 + lr][kk * 32 + lk]);
        acc[ni] = __builtin_amdgcn_mfma_f32_16x16x32_bf16(af, bg, acc[ni], 0, 0, 0);
      }
    }
  }

  const int crow = (lane >> 4) * 4, ccol = lane & 15;
  __syncthreads();
#pragma unroll
  for (int ni = 0; ni < 2; ++ni)
#pragma unroll
    for (int r = 0; r < 4; ++r)
      ft[m0 + crow + r][n0 + ni * 16 + ccol] = acc[ni][r];
  __syncthreads();

  if (bx < 16) {                         // q: rope+rms -> packed half2 qh
    const int h = bx;
#pragma unroll 2
    for (int rr = 0; rr < 8; ++rr) {
      int row = w * 8 + rr;
      int t = row0 + row;
      float vv = ft[row][lane];
      float pt = ft[row][lane ^ 32];
      int f = lane & 31;
      float c = cosb[t * 32 + f], s = sinb[t * 32 + f];
      float o = (lane < 32) ? (vv * c - pt * s) : (pt * s + vv * c);
      float ss = o * o;
#pragma unroll
      for (int off = 32; off; off >>= 1) ss += __shfl_xor(ss, off);
      float rN = rsqrtf(ss * (1.0f / 64.0f) + EPS_);
      uint hv = (uint)f2h(o * rN);
      uint nb = __shfl_down(hv, 1);
      if ((lane & 1) == 0)
        qh[(t * 16 + h) * 32 + (lane >> 1)] = hv | (nb << 16);
    }
    return;
  }
  if (bx < 24) {                         // k: rope+rms -> packed half2 K^T
    const int g = bx - 16;
#pragma unroll 2
    for (int rr = 0; rr < 8; ++rr) {
      int row = w * 8 + rr;
      int t = row0 + row;
      float vv = ft[row][lane];
      float pt = ft[row][lane ^ 32];
      int f = lane & 31;
      float c = cosb[t * 32 + f], s = sinb[t * 32 + f];
      float o = (lane < 32) ? (vv * c - pt * s) : (pt * s + vv * c);
      float ss = o * o;
#pragma unroll
      for (int off = 32; off; off >>= 1) ss += __shfl_xor(ss, off);
      ft[row][lane] = o * rsqrtf(ss * (1.0f / 64.0f) + EPS_);
    }
    __syncthreads();
#pragma unroll
    for (int it = 0; it < 4; ++it) {
      int idx2 = tid + it * 256;
      int d2 = idx2 >> 5, tt = idx2 & 31;
      uint lo = (uint)f2h(ft[tt][2 * d2]);
      uint hi = (uint)f2h(ft[tt][2 * d2 + 1]);
      kth[g * 16384 + d2 * 512 + row0 + tt] = lo | (hi << 16);
    }
    return;
  }
  // v: convert + transpose -> vt (bf16)
  const int g = bx - 24;
#pragma unroll
  for (int it = 0; it < 4; ++it) {
    int idx2 = tid + it * 256;
    int d = idx2 >> 4, tp = idx2 & 15;
    uint o = (uint)f2bf(ft[tp * 2][d]) | ((uint)f2bf(ft[tp * 2 + 1][d]) << 16);
    *reinterpret_cast<uint*>(&vt[g * 32768 + d * 512 + row0 + tp * 2]) = o;
  }
}

// ---------------------------------------------------------------------------
// out GEMM, 32x64 tiles (R17-proven).
// ---------------------------------------------------------------------------
__global__ __launch_bounds__(256) void out_mfma32_kernel(
    const ushort* __restrict__ yb, const ushort* __restrict__ Wto, float* __restrict__ out)
{
  __shared__ ushort At[32][72];
  __shared__ ushort Bs[64][72];
  const int tid = threadIdx.x;
  const int lane = tid & 63, w = tid >> 6;
  const int row0 = blockIdx.y * 32, col0 = blockIdx.x * 64;
  const int m0 = (w & 1) * 16, n0 = (w >> 1) * 32;
  const int lr = lane & 15, lk = (lane >> 4) * 8;
  f32x4 acc[2] = {};
  const int srA = tid >> 3, scA = (tid & 7) * 8;
  const int srB = tid >> 2, scB = (tid & 3) * 16;
  const ushort* Ap = &yb[(row0 + srA) * 1024 + scA];
  const ushort* Bp = &Wto[(col0 + srB) * 1024 + scB];

  for (int k0 = 0; k0 < 1024; k0 += 64) {
    __syncthreads();
    uint4 a0 = *reinterpret_cast<const uint4*>(Ap + k0);
    uint4 b0 = *reinterpret_cast<const uint4*>(Bp + k0);
    uint4 b1 = *reinterpret_cast<const uint4*>(Bp + k0 + 8);
    *reinterpret_cast<uint4*>(&At[srA][scA]) = a0;
    *reinterpret_cast<uint4*>(&Bs[srB][scB]) = b0;
    *reinterpret_cast<uint4*>(&Bs[srB][scB + 8]) = b1;
    __syncthreads();
#pragma unroll
    for (int kk = 0; kk < 2; ++kk) {
      bf16x8 af = *reinterpret_cast<const bf16x8*>(&At[m0 + lr][kk * 32 + lk]);
#pragma unroll
      for (int ni = 0; ni < 2; ++ni) {
        bf16x8 bg = *reinterpret_cast<const bf16x8*>(&Bs[n0 + ni * 16 + lr][kk * 32 + lk]);
        acc[ni] = __builtin_amdgcn_mfma_f32_16x16x32_bf16(af, bg, acc[ni], 0, 0, 0);
      }
    }
  }
  const int crow = (lane >> 4) * 4, ccol = lane & 15;
#pragma unroll
  for (int ni = 0; ni < 2; ++ni)
#pragma unroll
    for (int r = 0; r < 4; ++r)
      out[(row0 + m0 + crow + r) * 1024 + col0 + n0 + ni * 16 + ccol] = acc[ni][r];
}

// ---------------------------------------------------------------------------
// Fused attention v2: block = (head h, 16-row i-chunk) -> 512 blocks x 256
// thr (2 blocks/CU, heavy-first) for tail balance. Phase 1: wave w computes
// rows w*4..w*4+3 over all causal j-tiles into Ps[16][520] (packed-fp16
// score + exp, bit-identical P). Phase 2: per j-tile stage V [64][72]-style,
// MFMA P x V + ones-MFMA rowsum (wave w owns output cols w*16..+15).
// ---------------------------------------------------------------------------
__global__ __launch_bounds__(256) void attn_fused_kernel(
    const uint* __restrict__ qh, const uint* __restrict__ kth,
    const ushort* __restrict__ vt, ushort* __restrict__ yb)
{
  __shared__ __align__(16) ushort Ps[16][520];   // 16,640 B
  __shared__ __align__(16) ushort Vt[64][72];    //  9,216 B
  const int tid = threadIdx.x;
  const int w = tid >> 6, lane = tid & 63;
  const int bx = blockIdx.x;
  const int h = bx & 15;
  const int ic = 31 - (bx >> 4);        // heavy chunks first
  const int g = h >> 1;
  const int i0 = ic * 16;
  const int njt = (i0 >> 6) + 1;        // causal j-tiles of 64

  // ---- phase 1: scores + exp -> Ps (wave w: rows w*4..+3, all j-tiles)
  const half2v NEGBIG = {(_Float16)-60000.0f, (_Float16)-60000.0f};
  for (int jt = 0; jt < njt; ++jt) {
    const int j0 = jt * 64;
    const bool diag = (jt == njt - 1);
    half2v kreg[32];
    const uint* ktp = &kth[g * 16384 + j0 + lane];
#pragma unroll
    for (int d2 = 0; d2 < 32; ++d2) kreg[d2] = bch2(ktp[d2 * 512]);
#pragma unroll
    for (int q = 0; q < 4; ++q) {
      const int lrow = w * 4 + q;        // local row 0..15
      const int row = i0 + lrow;
      const uint4* qp4 = reinterpret_cast<const uint4*>(&qh[(row * 16 + h) * 32]);
      half2v m0 = NEGBIG, m1 = NEGBIG;
#pragma unroll
      for (int it = 0; it < 8; ++it) {
        uint4 qq = qp4[it];
        half2v a0 = bch2(qq.x) + kreg[it * 4 + 0];
        half2v a1 = bch2(qq.y) + kreg[it * 4 + 1];
        half2v a2 = bch2(qq.z) + kreg[it * 4 + 2];
        half2v a3 = bch2(qq.w) + kreg[it * 4 + 3];
        m0 = __builtin_elementwise_max(m0, __builtin_elementwise_max(a0, a1));
        m1 = __builtin_elementwise_max(m1, __builtin_elementwise_max(a2, a3));
      }
      half2v mm = __builtin_elementwise_max(m0, m1);
      float s = fmaxf((float)mm[0], (float)mm[1]);
      if (diag && (j0 + lane > row)) s = -INFINITY;
      Ps[lrow][j0 + lane] = f2bf(__expf(s));   // masked: exp(-inf)=0
    }
  }

  // ---- phase 2: y = (P @ V) / rowsum(P); wave w owns cols w*16..+15
  const int lr = lane & 15, lk8 = (lane >> 4) * 8;
  f32x4 acc = {}, accl = {};
  bf16x8 ones;
#pragma unroll
  for (int e = 0; e < 8; ++e) ones[e] = (short)0x3F80;
  const int srow = tid >> 2, scol = (tid & 3) * 16;    // 64 x 64 staging

  for (int jt = 0; jt < njt; ++jt) {
    __syncthreads();                    // jt=0: also the phase-1/2 barrier
    *reinterpret_cast<uint4*>(&Vt[srow][scol]) =
        *reinterpret_cast<const uint4*>(&vt[g * 32768 + srow * 512 + jt * 64 + scol]);
    *reinterpret_cast<uint4*>(&Vt[srow][scol + 8]) =
        *reinterpret_cast<const uint4*>(&vt[g * 32768 + srow * 512 + jt * 64 + scol + 8]);
    __syncthreads();
#pragma unroll
    for (int kk = 0; kk < 2; ++kk) {
      bf16x8 af = *reinterpret_cast<const bf16x8*>(&Ps[lr][jt * 64 + kk * 32 + lk8]);
      bf16x8 bg = *reinterpret_cast<const bf16x8*>(&Vt[w * 16 + lr][kk * 32 + lk8]);
      acc  = __builtin_amdgcn_mfma_f32_16x16x32_bf16(af, bg, acc, 0, 0, 0);
      accl = __builtin_amdgcn_mfma_f32_16x16x32_bf16(af, ones, accl, 0, 0, 0);
    }
  }

  const int crow = (lane >> 4) * 4, ccol = lane & 15;
#pragma unroll
  for (int r = 0; r < 4; ++r) {
    int i = i0 + crow + r;
    yb[i * 1024 + h * 64 + w * 16 + ccol] = f2bf(acc[r] / accl[r]);
  }
}

// ---------------------------------------------------------------------------
extern "C" void kernel_launch(void* const* d_in, const int* in_sizes, int n_in,
                              void* d_out, int out_size, void* d_ws, size_t ws_size,
                              hipStream_t stream) {
  const float* x    = (const float*)d_in[0];
  const float* cosb = (const float*)d_in[1];
  const float* sinb = (const float*)d_in[2];
  const float* Wq   = (const float*)d_in[3];
  const float* Wk   = (const float*)d_in[4];
  const float* Wv   = (const float*)d_in[5];
  const float* Wo   = (const float*)d_in[6];
  float* out = (float*)d_out;

  uint* wsu32 = (uint*)d_ws;
  uint*  kth  = wsu32;                     // 8x32x512 uint (half2 K^T)
  uint*  qh   = kth + 8 * 32 * 512;        // 512x16x32 uint (half2 q)
  ushort* xb  = (ushort*)(qh + TT * 16 * 32);  // 512x1024 bf16
  ushort* yb  = xb + TT * CC;              // 512x1024 bf16
  ushort* vtb = yb + TT * CC;              // 8x64x512 bf16 (V^T)
  ushort* Wtq = vtb + 8 * 64 * 512;        // 1024x1024 bf16
  ushort* Wtk = Wtq + CC * CC;             // 512x1024 bf16
  ushort* Wtv = Wtk + 512 * CC;            // 512x1024 bf16
  ushort* Wto = Wtv + 512 * CC;            // 1024x1024 bf16

  prep_kernel<<<dim3(1024), 256, 0, stream>>>(x, Wq, Wk, Wv, Wo, xb, Wtq, Wtk, Wtv, Wto);
  qkv_rope_kernel<<<dim3(32, 16), 256, 0, stream>>>(
      xb, Wtq, Wtk, Wtv, cosb, sinb, qh, kth, vtb);
  attn_fused_kernel<<<dim3(512), 256, 0, stream>>>(qh, kth, vtb, yb);
  out_mfma32_kernel<<<dim3(16, 16), 256, 0, stream>>>(yb, Wto, out);
}

// Round 23
// 45.663 us; speedup vs baseline: 1.8479x; 1.0148x over previous
//
#include <hip/hip_runtime.h>
#include <hip/hip_bf16.h>
#include <math.h>

#define TT 512
#define CC 1024
#define NH 16
#define NKV 8
#define HD 64
static constexpr float EPS_ = 1e-6f;

typedef short bf16x8 __attribute__((ext_vector_type(8)));
typedef float f32x4 __attribute__((ext_vector_type(4)));
typedef _Float16 half2v __attribute__((ext_vector_type(2)));

__device__ __forceinline__ ushort f2bf(float f) {
  union { __hip_bfloat16 h; ushort u; } cv;
  cv.h = __float2bfloat16(f);
  return cv.u;
}
__device__ __forceinline__ ushort f2h(float f) {
  union { _Float16 h; ushort u; } cv;
  cv.h = (_Float16)f;
  return cv.u;
}
__device__ __forceinline__ half2v bch2(uint u) {
  union { uint u; half2v h; } cv;
  cv.u = u;
  return cv.h;
}

// ---------------------------------------------------------------------------
// prep: x -> bf16 (same layout); Wq/Wk/Wv/Wo -> transposed bf16 Wt[n][k]
// ---------------------------------------------------------------------------
__global__ __launch_bounds__(256) void prep_kernel(
    const float* __restrict__ x,
    const float* __restrict__ Wq, const float* __restrict__ Wk,
    const float* __restrict__ Wv, const float* __restrict__ Wo,
    ushort* __restrict__ xb, ushort* __restrict__ Wtq, ushort* __restrict__ Wtk,
    ushort* __restrict__ Wtv, ushort* __restrict__ Wto)
{
  int b = blockIdx.x;
  if (b < 256) {
    int base = b * 2048 + threadIdx.x * 8;
    float4 f0 = *reinterpret_cast<const float4*>(&x[base]);
    float4 f1 = *reinterpret_cast<const float4*>(&x[base + 4]);
    union { ushort u[8]; uint4 v; } pk;
    pk.u[0] = f2bf(f0.x); pk.u[1] = f2bf(f0.y); pk.u[2] = f2bf(f0.z); pk.u[3] = f2bf(f0.w);
    pk.u[4] = f2bf(f1.x); pk.u[5] = f2bf(f1.y); pk.u[6] = f2bf(f1.z); pk.u[7] = f2bf(f1.w);
    *reinterpret_cast<uint4*>(&xb[base]) = pk.v;
    return;
  }
  b -= 256;
  const float* W; ushort* Wt; int ldW, tr, tc;
  if (b < 256)      { W = Wq; Wt = Wtq; ldW = 1024; tr = b >> 4;       tc = b & 15; }
  else if (b < 384) { int q = b - 256; W = Wk; Wt = Wtk; ldW = 512; tr = q >> 3; tc = q & 7; }
  else if (b < 512) { int q = b - 384; W = Wv; Wt = Wtv; ldW = 512; tr = q >> 3; tc = q & 7; }
  else              { int q = b - 512; W = Wo; Wt = Wto; ldW = 1024; tr = q >> 4; tc = q & 15; }
  const int k0 = tr * 64, n0 = tc * 64;
  __shared__ float ft[64][65];
  const int t = threadIdx.x;
#pragma unroll
  for (int it = 0; it < 4; ++it) {
    int q = t + it * 256;
    int r = q >> 4, c4 = q & 15;
    float4 f = *reinterpret_cast<const float4*>(&W[(k0 + r) * ldW + n0 + c4 * 4]);
    ft[r][c4 * 4 + 0] = f.x; ft[r][c4 * 4 + 1] = f.y;
    ft[r][c4 * 4 + 2] = f.z; ft[r][c4 * 4 + 3] = f.w;
  }
  __syncthreads();
#pragma unroll
  for (int it = 0; it < 2; ++it) {
    int q = t + it * 256;
    int n = q >> 3, kc = q & 7;
    union { ushort u[8]; uint4 v; } pk;
#pragma unroll
    for (int j = 0; j < 8; ++j) pk.u[j] = f2bf(ft[kc * 8 + j][n]);
    *reinterpret_cast<uint4*>(&Wt[(n0 + n) * 1024 + k0 + kc * 8]) = pk.v;
  }
}

// ---------------------------------------------------------------------------
// Fused QKV GEMM + rope/rms/pack epilogue (R21-proven). 32x64 tiles,
// grid (32,16) = 512 blocks, BK=128.
// ---------------------------------------------------------------------------
__global__ __launch_bounds__(256) void qkv_rope_kernel(
    const ushort* __restrict__ xb,
    const ushort* __restrict__ Wtq, const ushort* __restrict__ Wtk, const ushort* __restrict__ Wtv,
    const float* __restrict__ cosb, const float* __restrict__ sinb,
    uint* __restrict__ qh, uint* __restrict__ kth, ushort* __restrict__ vt)
{
  __shared__ ushort At[32][136];
  __shared__ ushort Bs[64][136];
  __shared__ float ft[32][65];
  const int tid = threadIdx.x;
  const int lane = tid & 63, w = tid >> 6;
  const int bx = blockIdx.x, by = blockIdx.y;
  const int row0 = by * 32;

  const ushort* Bt; int col0;
  if (bx < 16)      { Bt = Wtq; col0 = bx * 64; }
  else if (bx < 24) { Bt = Wtk; col0 = (bx - 16) * 64; }
  else              { Bt = Wtv; col0 = (bx - 24) * 64; }

  const int m0 = (w & 1) * 16, n0 = (w >> 1) * 32;
  const int lr = lane & 15, lk = (lane >> 4) * 8;
  f32x4 acc[2] = {};
  const int srA = tid >> 3, scA = (tid & 7) * 16;
  const int srB = tid >> 2, scB = (tid & 3) * 32;
  const ushort* Ap = &xb[(row0 + srA) * 1024 + scA];
  const ushort* Bp = &Bt[(col0 + srB) * 1024 + scB];

  for (int k0 = 0; k0 < 1024; k0 += 128) {
    __syncthreads();
    uint4 a0 = *reinterpret_cast<const uint4*>(Ap + k0);
    uint4 a1 = *reinterpret_cast<const uint4*>(Ap + k0 + 8);
    uint4 b0 = *reinterpret_cast<const uint4*>(Bp + k0);
    uint4 b1 = *reinterpret_cast<const uint4*>(Bp + k0 + 8);
    uint4 b2 = *reinterpret_cast<const uint4*>(Bp + k0 + 16);
    uint4 b3 = *reinterpret_cast<const uint4*>(Bp + k0 + 24);
    *reinterpret_cast<uint4*>(&At[srA][scA]) = a0;
    *reinterpret_cast<uint4*>(&At[srA][scA + 8]) = a1;
    *reinterpret_cast<uint4*>(&Bs[srB][scB]) = b0;
    *reinterpret_cast<uint4*>(&Bs[srB][scB + 8]) = b1;
    *reinterpret_cast<uint4*>(&Bs[srB][scB + 16]) = b2;
    *reinterpret_cast<uint4*>(&Bs[srB][scB + 24]) = b3;
    __syncthreads();
#pragma unroll
    for (int kk = 0; kk < 4; ++kk) {
      bf16x8 af = *reinterpret_cast<const bf16x8*>(&At[m0 + lr][kk * 32 + lk]);
#pragma unroll
      for (int ni = 0; ni < 2; ++ni) {
        bf16x8 bg = *reinterpret_cast<const bf16x8*>(&Bs[n0 + ni * 16 + lr][kk * 32 + lk]);
        acc[ni] = __builtin_amdgcn_mfma_f32_16x16x32_bf16(af, bg, acc[ni], 0, 0, 0);
      }
    }
  }

  const int crow = (lane >> 4) * 4, ccol = lane & 15;
  __syncthreads();
#pragma unroll
  for (int ni = 0; ni < 2; ++ni)
#pragma unroll
    for (int r = 0; r < 4; ++r)
      ft[m0 + crow + r][n0 + ni * 16 + ccol] = acc[ni][r];
  __syncthreads();

  if (bx < 16) {                         // q: rope+rms -> packed half2 qh
    const int h = bx;
#pragma unroll 2
    for (int rr = 0; rr < 8; ++rr) {
      int row = w * 8 + rr;
      int t = row0 + row;
      float vv = ft[row][lane];
      float pt = ft[row][lane ^ 32];
      int f = lane & 31;
      float c = cosb[t * 32 + f], s = sinb[t * 32 + f];
      float o = (lane < 32) ? (vv * c - pt * s) : (pt * s + vv * c);
      float ss = o * o;
#pragma unroll
      for (int off = 32; off; off >>= 1) ss += __shfl_xor(ss, off);
      float rN = rsqrtf(ss * (1.0f / 64.0f) + EPS_);
      uint hv = (uint)f2h(o * rN);
      uint nb = __shfl_down(hv, 1);
      if ((lane & 1) == 0)
        qh[(t * 16 + h) * 32 + (lane >> 1)] = hv | (nb << 16);
    }
    return;
  }
  if (bx < 24) {                         // k: rope+rms -> packed half2 K^T
    const int g = bx - 16;
#pragma unroll 2
    for (int rr = 0; rr < 8; ++rr) {
      int row = w * 8 + rr;
      int t = row0 + row;
      float vv = ft[row][lane];
      float pt = ft[row][lane ^ 32];
      int f = lane & 31;
      float c = cosb[t * 32 + f], s = sinb[t * 32 + f];
      float o = (lane < 32) ? (vv * c - pt * s) : (pt * s + vv * c);
      float ss = o * o;
#pragma unroll
      for (int off = 32; off; off >>= 1) ss += __shfl_xor(ss, off);
      ft[row][lane] = o * rsqrtf(ss * (1.0f / 64.0f) + EPS_);
    }
    __syncthreads();
#pragma unroll
    for (int it = 0; it < 4; ++it) {
      int idx2 = tid + it * 256;
      int d2 = idx2 >> 5, tt = idx2 & 31;
      uint lo = (uint)f2h(ft[tt][2 * d2]);
      uint hi = (uint)f2h(ft[tt][2 * d2 + 1]);
      kth[g * 16384 + d2 * 512 + row0 + tt] = lo | (hi << 16);
    }
    return;
  }
  // v: convert + transpose -> vt (bf16)
  const int g = bx - 24;
#pragma unroll
  for (int it = 0; it < 4; ++it) {
    int idx2 = tid + it * 256;
    int d = idx2 >> 4, tp = idx2 & 15;
    uint o = (uint)f2bf(ft[tp * 2][d]) | ((uint)f2bf(ft[tp * 2 + 1][d]) << 16);
    *reinterpret_cast<uint*>(&vt[g * 32768 + d * 512 + row0 + tp * 2]) = o;
  }
}

// ---------------------------------------------------------------------------
// out GEMM, 16x64 tiles: grid (16,32) = 512 blocks (2/CU, was 1/CU).
// Wave w owns output cols w*16..+15; A-fragment shared across waves.
// ---------------------------------------------------------------------------
__global__ __launch_bounds__(256) void out_mfma16_kernel(
    const ushort* __restrict__ yb, const ushort* __restrict__ Wto, float* __restrict__ out)
{
  __shared__ ushort At[16][72];
  __shared__ ushort Bs[64][72];
  const int tid = threadIdx.x;
  const int lane = tid & 63, w = tid >> 6;
  const int row0 = blockIdx.y * 16, col0 = blockIdx.x * 64;
  const int lr = lane & 15, lk = (lane >> 4) * 8;
  f32x4 acc = {};
  const int srA = tid >> 4, scA = (tid & 15) * 4;   // 16 rows x 64 k, uint2
  const int srB = tid >> 2, scB = (tid & 3) * 16;   // 64 rows x 64 k, uint4
  const ushort* Ap = &yb[(row0 + srA) * 1024 + scA];
  const ushort* Bp = &Wto[(col0 + srB) * 1024 + scB];

  for (int k0 = 0; k0 < 1024; k0 += 64) {
    __syncthreads();
    uint2 a0 = *reinterpret_cast<const uint2*>(Ap + k0);
    uint4 b0 = *reinterpret_cast<const uint4*>(Bp + k0);
    uint4 b1 = *reinterpret_cast<const uint4*>(Bp + k0 + 8);
    *reinterpret_cast<uint2*>(&At[srA][scA]) = a0;
    *reinterpret_cast<uint4*>(&Bs[srB][scB]) = b0;
    *reinterpret_cast<uint4*>(&Bs[srB][scB + 8]) = b1;
    __syncthreads();
#pragma unroll
    for (int kk = 0; kk < 2; ++kk) {
      bf16x8 af = *reinterpret_cast<const bf16x8*>(&At[lr][kk * 32 + lk]);
      bf16x8 bg = *reinterpret_cast<const bf16x8*>(&Bs[w * 16 + lr][kk * 32 + lk]);
      acc = __builtin_amdgcn_mfma_f32_16x16x32_bf16(af, bg, acc, 0, 0, 0);
    }
  }
  const int crow = (lane >> 4) * 4, ccol = lane & 15;
#pragma unroll
  for (int r = 0; r < 4; ++r)
    out[(row0 + crow + r) * 1024 + col0 + w * 16 + ccol] = acc[r];
}

// ---------------------------------------------------------------------------
// Fused attention v2 (R21-proven): block = (head h, 16-row i-chunk) ->
// 512 blocks x 256 thr, heavy-first. Phase 1: packed-fp16 scores -> Ps.
// Phase 2: MFMA P x V + ones-MFMA rowsum, divide, write y.
// ---------------------------------------------------------------------------
__global__ __launch_bounds__(256) void attn_fused_kernel(
    const uint* __restrict__ qh, const uint* __restrict__ kth,
    const ushort* __restrict__ vt, ushort* __restrict__ yb)
{
  __shared__ __align__(16) ushort Ps[16][520];
  __shared__ __align__(16) ushort Vt[64][72];
  const int tid = threadIdx.x;
  const int w = tid >> 6, lane = tid & 63;
  const int bx = blockIdx.x;
  const int h = bx & 15;
  const int ic = 31 - (bx >> 4);        // heavy chunks first
  const int g = h >> 1;
  const int i0 = ic * 16;
  const int njt = (i0 >> 6) + 1;

  const half2v NEGBIG = {(_Float16)-60000.0f, (_Float16)-60000.0f};
  for (int jt = 0; jt < njt; ++jt) {
    const int j0 = jt * 64;
    const bool diag = (jt == njt - 1);
    half2v kreg[32];
    const uint* ktp = &kth[g * 16384 + j0 + lane];
#pragma unroll
    for (int d2 = 0; d2 < 32; ++d2) kreg[d2] = bch2(ktp[d2 * 512]);
#pragma unroll
    for (int q = 0; q < 4; ++q) {
      const int lrow = w * 4 + q;
      const int row = i0 + lrow;
      const uint4* qp4 = reinterpret_cast<const uint4*>(&qh[(row * 16 + h) * 32]);
      half2v m0 = NEGBIG, m1 = NEGBIG;
#pragma unroll
      for (int it = 0; it < 8; ++it) {
        uint4 qq = qp4[it];
        half2v a0 = bch2(qq.x) + kreg[it * 4 + 0];
        half2v a1 = bch2(qq.y) + kreg[it * 4 + 1];
        half2v a2 = bch2(qq.z) + kreg[it * 4 + 2];
        half2v a3 = bch2(qq.w) + kreg[it * 4 + 3];
        m0 = __builtin_elementwise_max(m0, __builtin_elementwise_max(a0, a1));
        m1 = __builtin_elementwise_max(m1, __builtin_elementwise_max(a2, a3));
      }
      half2v mm = __builtin_elementwise_max(m0, m1);
      float s = fmaxf((float)mm[0], (float)mm[1]);
      if (diag && (j0 + lane > row)) s = -INFINITY;
      Ps[lrow][j0 + lane] = f2bf(__expf(s));
    }
  }

  const int lr = lane & 15, lk8 = (lane >> 4) * 8;
  f32x4 acc = {}, accl = {};
  bf16x8 ones;
#pragma unroll
  for (int e = 0; e < 8; ++e) ones[e] = (short)0x3F80;
  const int srow = tid >> 2, scol = (tid & 3) * 16;

  for (int jt = 0; jt < njt; ++jt) {
    __syncthreads();
    *reinterpret_cast<uint4*>(&Vt[srow][scol]) =
        *reinterpret_cast<const uint4*>(&vt[g * 32768 + srow * 512 + jt * 64 + scol]);
    *reinterpret_cast<uint4*>(&Vt[srow][scol + 8]) =
        *reinterpret_cast<const uint4*>(&vt[g * 32768 + srow * 512 + jt * 64 + scol + 8]);
    __syncthreads();
#pragma unroll
    for (int kk = 0; kk < 2; ++kk) {
      bf16x8 af = *reinterpret_cast<const bf16x8*>(&Ps[lr][jt * 64 + kk * 32 + lk8]);
      bf16x8 bg = *reinterpret_cast<const bf16x8*>(&Vt[w * 16 + lr][kk * 32 + lk8]);
      acc  = __builtin_amdgcn_mfma_f32_16x16x32_bf16(af, bg, acc, 0, 0, 0);
      accl = __builtin_amdgcn_mfma_f32_16x16x32_bf16(af, ones, accl, 0, 0, 0);
    }
  }

  const int crow = (lane >> 4) * 4, ccol = lane & 15;
#pragma unroll
  for (int r = 0; r < 4; ++r) {
    int i = i0 + crow + r;
    yb[i * 1024 + h * 64 + w * 16 + ccol] = f2bf(acc[r] / accl[r]);
  }
}

// ---------------------------------------------------------------------------
extern "C" void kernel_launch(void* const* d_in, const int* in_sizes, int n_in,
                              void* d_out, int out_size, void* d_ws, size_t ws_size,
                              hipStream_t stream) {
  const float* x    = (const float*)d_in[0];
  const float* cosb = (const float*)d_in[1];
  const float* sinb = (const float*)d_in[2];
  const float* Wq   = (const float*)d_in[3];
  const float* Wk   = (const float*)d_in[4];
  const float* Wv   = (const float*)d_in[5];
  const float* Wo   = (const float*)d_in[6];
  float* out = (float*)d_out;

  uint* wsu32 = (uint*)d_ws;
  uint*  kth  = wsu32;                     // 8x32x512 uint (half2 K^T)
  uint*  qh   = kth + 8 * 32 * 512;        // 512x16x32 uint (half2 q)
  ushort* xb  = (ushort*)(qh + TT * 16 * 32);  // 512x1024 bf16
  ushort* yb  = xb + TT * CC;              // 512x1024 bf16
  ushort* vtb = yb + TT * CC;              // 8x64x512 bf16 (V^T)
  ushort* Wtq = vtb + 8 * 64 * 512;        // 1024x1024 bf16
  ushort* Wtk = Wtq + CC * CC;             // 512x1024 bf16
  ushort* Wtv = Wtk + 512 * CC;            // 512x1024 bf16
  ushort* Wto = Wtv + 512 * CC;            // 1024x1024 bf16

  prep_kernel<<<dim3(1024), 256, 0, stream>>>(x, Wq, Wk, Wv, Wo, xb, Wtq, Wtk, Wtv, Wto);
  qkv_rope_kernel<<<dim3(32, 16), 256, 0, stream>>>(
      xb, Wtq, Wtk, Wtv, cosb, sinb, qh, kth, vtb);
  attn_fused_kernel<<<dim3(512), 256, 0, stream>>>(qh, kth, vtb, yb);
  out_mfma16_kernel<<<dim3(16, 32), 256, 0, stream>>>(yb, Wto, out);
}